// Round 5
// baseline (1025.052 us; speedup 1.0000x reference)
//
#include <hip/hip_runtime.h>
#include <math.h>

#define D 1024
#define V 16384
#define NROWS 8192

typedef __bf16 bf16_t;
typedef bf16_t bf16x8 __attribute__((ext_vector_type(8)));
typedef float f32x4 __attribute__((ext_vector_type(4)));

__device__ __forceinline__ unsigned int sortable_key(float v) {
    unsigned int b = __float_as_uint(v);
    return (b & 0x80000000u) ? ~b : (b | 0x80000000u);
}

// split float4 -> bf16 hi (truncate) + bf16 lo (truncate of x - hi)
__device__ __forceinline__ void split4(float4 v, uint2& hw, uint2& lw) {
    unsigned int u0 = __float_as_uint(v.x), u1 = __float_as_uint(v.y);
    unsigned int u2 = __float_as_uint(v.z), u3 = __float_as_uint(v.w);
    float l0 = v.x - __uint_as_float(u0 & 0xFFFF0000u);
    float l1 = v.y - __uint_as_float(u1 & 0xFFFF0000u);
    float l2 = v.z - __uint_as_float(u2 & 0xFFFF0000u);
    float l3 = v.w - __uint_as_float(u3 & 0xFFFF0000u);
    hw.x = (u0 >> 16) | (u1 & 0xFFFF0000u);
    hw.y = (u2 >> 16) | (u3 & 0xFFFF0000u);
    lw.x = (__float_as_uint(l0) >> 16) | (__float_as_uint(l1) & 0xFFFF0000u);
    lw.y = (__float_as_uint(l2) >> 16) | (__float_as_uint(l3) & 0xFFFF0000u);
}

// ---------------- row L2-norm ----------------
__global__ __launch_bounds__(256) void rownorm_kernel(const float* __restrict__ M,
                                                      float* __restrict__ R, int nrows) {
    int tid = threadIdx.x;
    int row = blockIdx.x * 4 + (tid >> 6);
    int lane = tid & 63;
    if (row >= nrows) return;
    const float4* p = (const float4*)(M + (size_t)row * D);
    float ss = 0.f;
#pragma unroll
    for (int i = 0; i < 4; ++i) {
        float4 v = p[lane + 64 * i];
        ss += v.x * v.x + v.y * v.y + v.z * v.z + v.w * v.w;
    }
#pragma unroll
    for (int m = 32; m >= 1; m >>= 1) ss += __shfl_xor(ss, m, 64);
    if (lane == 0) R[row] = rsqrtf(fmaxf(ss, 1e-12f));
}

__global__ __launch_bounds__(256) void zero_kernel(unsigned long long* __restrict__ p, int n) {
    int i = blockIdx.x * 256 + threadIdx.x;
    if (i < n) p[i] = 0ull;
}

// ---------------- pre-split X into fragment-packed bf16 hi/lo ----------------
__global__ __launch_bounds__(256) void xsplit_kernel(const float* __restrict__ X,
                                                     ushort* __restrict__ Xhi,
                                                     ushort* __restrict__ Xlo) {
    int f = blockIdx.x * 256 + threadIdx.x;
    int row = f >> 8;
    int kq = f & 255;
    int k0 = kq * 4;
    float4 v = *((const float4*)(X + (size_t)row * D) + kq);
    uint2 hw, lw;
    split4(v, hw, lw);
    int t16 = row >> 4, m = row & 15;
    int kc = k0 >> 5, kk = k0 & 31;
    int lane = m | ((kk >> 3) << 4);
    int j0 = kk & 4;
    int idx = ((t16 * 32 + kc) * 64 + lane) * 8 + j0;
    *(uint2*)(Xhi + idx) = hw;
    *(uint2*)(Xlo + idx) = lw;
}

// ---------------- sim GEMM: bf16 3-pass (hh+hl+lh) MFMA + fused argmax ----------------
// tile 128 rows x 256 cols; A direct from pre-split global; B ping-pong LDS, 1 barrier/kc.
// XCD swizzle: cw=(lin&7)+8*(lin>>9), rt=(lin>>3)&63 -> each XCD works one W col-tile at a time.
__global__ __launch_bounds__(256, 2) void gemm1_kernel(const ushort* __restrict__ Xhi,
                                                       const ushort* __restrict__ Xlo,
                                                       const float* __restrict__ W,
                                                       const float* __restrict__ RK,
                                                       unsigned long long* __restrict__ packed) {
    __shared__ ushort Bh[2][16][64][8];
    __shared__ ushort Bl[2][16][64][8];
    __shared__ unsigned long long red[128][2];

    const int tid = threadIdx.x;
    const int l = tid & 63;
    const int wave = tid >> 6;
    const int wy = wave >> 1, wx = wave & 1;   // wave tile: 64 rows x 128 cols
    const int lin = blockIdx.x;
    const int cwTile = (lin & 7) + 8 * (lin >> 9);
    const int rowTile = (lin >> 3) & 63;
    const int rowBase = rowTile * 128;
    const int cwBase  = cwTile * 256;

    f32x4 acc[4][8];
#pragma unroll
    for (int mt = 0; mt < 4; ++mt)
#pragma unroll
        for (int nt = 0; nt < 8; ++nt) acc[mt][nt] = (f32x4)0.f;

    const float4* Wb = (const float4*)(W + (size_t)cwBase * D);

    float4 pb[8];
#pragma unroll
    for (int i = 0; i < 8; ++i) {
        int f = i * 256 + tid;
        int row = f >> 3, kq = f & 7;
        pb[i] = Wb[row * (D / 4) + kq];
    }

    const int t16base = rowTile * 8 + wy * 4;

    for (int kc = 0; kc < 32; ++kc) {
        const int b = kc & 1;
        // A-frag global loads for current kc — issue before the split so latency
        // hides behind split VALU; drained by the barrier right before MFMA.
        bf16x8 ah[4], al[4];
#pragma unroll
        for (int mt = 0; mt < 4; ++mt) {
            int off = (((t16base + mt) * 32 + kc) * 64 + l) * 8;
            ah[mt] = *(const bf16x8*)(Xhi + off);
            al[mt] = *(const bf16x8*)(Xlo + off);
        }
        // B split + stage into ping-pong buffer b
#pragma unroll
        for (int i = 0; i < 8; ++i) {
            int f = i * 256 + tid;
            int row = f >> 3, kq = f & 7;
            int tile = row >> 4;
            int lf = (row & 15) | ((kq >> 1) << 4);
            int j0 = (kq & 1) * 4;
            uint2 hw, lw;
            split4(pb[i], hw, lw);
            *(uint2*)&Bh[b][tile][lf][j0] = hw;
            *(uint2*)&Bl[b][tile][lf][j0] = lw;
        }
        __syncthreads();
        // pb prefetch for next kc — issued after the barrier so the compiler's
        // vmcnt(0)-at-barrier drain doesn't serialize it.
        if (kc < 31) {
#pragma unroll
            for (int i = 0; i < 8; ++i) {
                int f = i * 256 + tid;
                int row = f >> 3, kq = f & 7;
                pb[i] = Wb[row * (D / 4) + (kc + 1) * 8 + kq];
            }
        }
#pragma unroll
        for (int nt = 0; nt < 8; ++nt) {
            bf16x8 bh = *(const bf16x8*)&Bh[b][wx * 8 + nt][l][0];
            bf16x8 bl = *(const bf16x8*)&Bl[b][wx * 8 + nt][l][0];
#pragma unroll
            for (int mt = 0; mt < 4; ++mt) {
                acc[mt][nt] = __builtin_amdgcn_mfma_f32_16x16x32_bf16(ah[mt], bh, acc[mt][nt], 0, 0, 0);
                acc[mt][nt] = __builtin_amdgcn_mfma_f32_16x16x32_bf16(ah[mt], bl, acc[mt][nt], 0, 0, 0);
                acc[mt][nt] = __builtin_amdgcn_mfma_f32_16x16x32_bf16(al[mt], bh, acc[mt][nt], 0, 0, 0);
            }
        }
        // NOTE: no second barrier — ping-pong buffer b^1 is written next iter while
        // b is read; writes to b again are fenced by the NEXT iteration's barrier.
    }

    // epilogue: scale by rk, per-row argmax over this block's 256 cols
    const int q = l >> 4, c = l & 15;
    float rk_l[8];
#pragma unroll
    for (int nt = 0; nt < 8; ++nt) rk_l[nt] = RK[cwBase + wx * 128 + nt * 16 + c];
#pragma unroll
    for (int mt = 0; mt < 4; ++mt) {
#pragma unroll
        for (int r = 0; r < 4; ++r) {
            float best = -INFINITY;
            int bcol = 0x7fffffff;
#pragma unroll
            for (int nt = 0; nt < 8; ++nt) {
                float v = acc[mt][nt][r] * rk_l[nt];
                int col = cwBase + wx * 128 + nt * 16 + c;
                if (v > best || (v == best && col < bcol)) { best = v; bcol = col; }
            }
            unsigned long long pk = ((unsigned long long)sortable_key(best) << 32) |
                                    (unsigned long long)(~(unsigned int)bcol);
#pragma unroll
            for (int m = 1; m < 16; m <<= 1) {
                unsigned long long o = __shfl_xor(pk, m, 64);
                if (o > pk) pk = o;
            }
            if (c == 0) red[wy * 64 + mt * 16 + q * 4 + r][wx] = pk;
        }
    }
    __syncthreads();
    if (tid < 128) {
        unsigned long long a = red[tid][0], bb = red[tid][1];
        if (bb > a) a = bb;
        atomicMax(packed + (rowBase + tid), a);
    }
}

// ---------------- unpack argmax results ----------------
__global__ __launch_bounds__(256) void finalize_kernel(const unsigned long long* __restrict__ packed,
                                                       const float* __restrict__ RQ,
                                                       float* __restrict__ outIdx,
                                                       float* __restrict__ outSim,
                                                       int* __restrict__ idxArr) {
    int row = blockIdx.x * 256 + threadIdx.x;
    if (row >= NROWS) return;
    unsigned long long p = packed[row];
    unsigned int key = (unsigned int)(p >> 32);
    unsigned int b = (key & 0x80000000u) ? (key & 0x7FFFFFFFu) : ~key;
    int idx = (int)(~(unsigned int)(p & 0xFFFFFFFFull));
    outIdx[row] = (float)idx;
    outSim[row] = __uint_as_float(b) * RQ[row];
    idxArr[row] = idx;
}

// ---------------- per-row LN stats ----------------
__global__ __launch_bounds__(256) void ln_stats_kernel(const float* __restrict__ X,
                                                       const float* __restrict__ W,
                                                       const int* __restrict__ idxArr,
                                                       float* __restrict__ MU,
                                                       float* __restrict__ RS) {
    __shared__ float red[8];
    int row = blockIdx.x;
    int tid = threadIdx.x;
    int idx = idxArr[row];
    float4 z  = *((const float4*)(W + (size_t)idx * D) + tid);
    float4 xv = *((const float4*)(X + (size_t)row * D) + tid);
    float4 e;
    e.x = (z.x - xv.x) + xv.x;
    e.y = (z.y - xv.y) + xv.y;
    e.z = (z.z - xv.z) + xv.z;
    e.w = (z.w - xv.w) + xv.w;
    float s  = e.x + e.y + e.z + e.w;
    float s2 = e.x * e.x + e.y * e.y + e.z * e.z + e.w * e.w;
#pragma unroll
    for (int m = 32; m >= 1; m >>= 1) {
        s  += __shfl_xor(s, m, 64);
        s2 += __shfl_xor(s2, m, 64);
    }
    int wave = tid >> 6, lane = tid & 63;
    if (lane == 0) { red[wave] = s; red[4 + wave] = s2; }
    __syncthreads();
    if (tid == 0) {
        s  = red[0] + red[1] + red[2] + red[3];
        s2 = red[4] + red[5] + red[6] + red[7];
        float mean = s * (1.f / D);
        float var  = s2 * (1.f / D) - mean * mean;
        MU[row] = mean;
        RS[row] = rsqrtf(var + 1e-6f);
    }
}

// ---------------- projection GEMM: bf16 3-pass MFMA, LN fused into A staging ----------------
__global__ __launch_bounds__(256, 2) void gemm2_kernel(const float* __restrict__ X,
                                                       const float* __restrict__ W,
                                                       const int* __restrict__ idxArr,
                                                       const float* __restrict__ MU,
                                                       const float* __restrict__ RS,
                                                       const float* __restrict__ gamma,
                                                       const float* __restrict__ beta,
                                                       const float* __restrict__ B,
                                                       float* __restrict__ Out) {
    __shared__ ushort Ah[8][64][8];
    __shared__ ushort Al[8][64][8];
    __shared__ ushort Bh[8][64][8];
    __shared__ ushort Bl[8][64][8];

    const int tid = threadIdx.x;
    const int l = tid & 63;
    const int wave = tid >> 6;
    const int wy = wave >> 1, wx = wave & 1;
    const int rowBase = blockIdx.y * 128;
    const int nBase   = blockIdx.x * 128;

    f32x4 acc[4][4];
#pragma unroll
    for (int mt = 0; mt < 4; ++mt)
#pragma unroll
        for (int nt = 0; nt < 4; ++nt) acc[mt][nt] = (f32x4)0.f;

    int arow[4], aidx[4];
    float amu[4], ars[4];
#pragma unroll
    for (int i = 0; i < 4; ++i) {
        int f = i * 256 + tid;
        arow[i] = f >> 3;
        int grow = rowBase + arow[i];
        aidx[i] = idxArr[grow];
        amu[i] = MU[grow];
        ars[i] = RS[grow];
    }

    for (int kc = 0; kc < 32; ++kc) {
        __syncthreads();
#pragma unroll
        for (int i = 0; i < 4; ++i) {
            int f = i * 256 + tid;
            int row = arow[i], kq = f & 7;
            int col = kc * 32 + kq * 4;
            float4 z  = *(const float4*)(W + (size_t)aidx[i] * D + col);
            float4 xv = *(const float4*)(X + (size_t)(rowBase + row) * D + col);
            float4 g  = *(const float4*)(gamma + col);
            float4 bb = *(const float4*)(beta + col);
            float4 a;
        a.x = (((z.x - xv.x) + xv.x) - amu[i]) * ars[i] * g.x + bb.x;
        a.y = (((z.y - xv.y) + xv.y) - amu[i]) * ars[i] * g.y + bb.y;
        a.z = (((z.z - xv.z) + xv.z) - amu[i]) * ars[i] * g.z + bb.z;
        a.w = (((z.w - xv.w) + xv.w) - amu[i]) * ars[i] * g.w + bb.w;
            uint2 hw, lw;
            split4(a, hw, lw);
            int tile = row >> 4;
            int lf = (row & 15) | ((kq >> 1) << 4);
            int j0 = (kq & 1) * 4;
            *(uint2*)&Ah[tile][lf][j0] = hw;
            *(uint2*)&Al[tile][lf][j0] = lw;
        }
#pragma unroll
        for (int i = 0; i < 4; ++i) {
            int f = i * 256 + tid;
            int n = f & 127, dq = f >> 7;
            const float* bp = B + (size_t)(kc * 32 + dq * 4) * D + nBase + n;
            float b0 = bp[0], b1 = bp[D], b2 = bp[2 * D], b3 = bp[3 * D];
            float4 v = {b0, b1, b2, b3};
            uint2 hw, lw;
            split4(v, hw, lw);
            int tile = n >> 4;
            int lf = (n & 15) | ((dq >> 1) << 4);
            int j0 = (dq & 1) * 4;
            *(uint2*)&Bh[tile][lf][j0] = hw;
            *(uint2*)&Bl[tile][lf][j0] = lw;
        }
        __syncthreads();
        bf16x8 ah[4], al[4];
#pragma unroll
        for (int mt = 0; mt < 4; ++mt) {
            ah[mt] = *(const bf16x8*)&Ah[wy * 4 + mt][l][0];
            al[mt] = *(const bf16x8*)&Al[wy * 4 + mt][l][0];
        }
#pragma unroll
        for (int nt = 0; nt < 4; ++nt) {
            bf16x8 bh = *(const bf16x8*)&Bh[wx * 4 + nt][l][0];
            bf16x8 bl = *(const bf16x8*)&Bl[wx * 4 + nt][l][0];
#pragma unroll
            for (int mt = 0; mt < 4; ++mt) {
                acc[mt][nt] = __builtin_amdgcn_mfma_f32_16x16x32_bf16(ah[mt], bh, acc[mt][nt], 0, 0, 0);
                acc[mt][nt] = __builtin_amdgcn_mfma_f32_16x16x32_bf16(ah[mt], bl, acc[mt][nt], 0, 0, 0);
                acc[mt][nt] = __builtin_amdgcn_mfma_f32_16x16x32_bf16(al[mt], bh, acc[mt][nt], 0, 0, 0);
            }
        }
    }

    const int q = l >> 4, c = l & 15;
#pragma unroll
    for (int mt = 0; mt < 4; ++mt)
#pragma unroll
        for (int nt = 0; nt < 4; ++nt)
#pragma unroll
            for (int r = 0; r < 4; ++r) {
                int grow = rowBase + wy * 64 + mt * 16 + q * 4 + r;
                int gcol = nBase + wx * 64 + nt * 16 + c;
                Out[(size_t)grow * D + gcol] = acc[mt][nt][r];
            }
}

extern "C" void kernel_launch(void* const* d_in, const int* in_sizes, int n_in,
                              void* d_out, int out_size, void* d_ws, size_t ws_size,
                              hipStream_t stream) {
    const float* X     = (const float*)d_in[0];
    const float* W     = (const float*)d_in[1];
    const float* gamma = (const float*)d_in[2];
    const float* beta  = (const float*)d_in[3];
    const float* OW    = (const float*)d_in[4];

    float* out    = (float*)d_out;
    float* outIdx = out;
    float* outSim = out + NROWS;
    float* outO   = out + 2 * NROWS;

    // Xsplit scratch lives in the outO region (32 MB; overwritten by gemm2 at the end)
    ushort* Xhi = (ushort*)outO;
    ushort* Xlo = Xhi + (size_t)NROWS * D;

    // workspace — 256 KB
    unsigned long long* packed = (unsigned long long*)d_ws;
    float* RK     = (float*)(packed + NROWS);
    float* RQ     = RK + V;
    float* MU     = RQ + NROWS;
    float* RS     = MU + NROWS;
    int*   idxArr = (int*)(RS + NROWS);

    hipLaunchKernelGGL(rownorm_kernel, dim3(V / 4), dim3(256), 0, stream, W, RK, V);
    hipLaunchKernelGGL(rownorm_kernel, dim3(NROWS / 4), dim3(256), 0, stream, X, RQ, NROWS);
    hipLaunchKernelGGL(zero_kernel, dim3(NROWS / 256), dim3(256), 0, stream, packed, NROWS);
    hipLaunchKernelGGL(xsplit_kernel, dim3(NROWS * (D / 4) / 256), dim3(256), 0, stream, X, Xhi, Xlo);
    hipLaunchKernelGGL(gemm1_kernel, dim3((V / 256) * (NROWS / 128)), dim3(256), 0, stream,
                       Xhi, Xlo, W, RK, packed);
    hipLaunchKernelGGL(finalize_kernel, dim3(NROWS / 256), dim3(256), 0, stream, packed, RQ, outIdx, outSim, idxArr);
    hipLaunchKernelGGL(ln_stats_kernel, dim3(NROWS), dim3(256), 0, stream, X, W, idxArr, MU, RS);
    hipLaunchKernelGGL(gemm2_kernel, dim3(D / 128, NROWS / 128), dim3(256), 0, stream,
                       X, W, idxArr, MU, RS, gamma, beta, OW, outO);
}

// Round 6
// 730.603 us; speedup vs baseline: 1.4030x; 1.4030x over previous
//
#include <hip/hip_runtime.h>
#include <math.h>

#define D 1024
#define V 16384
#define NROWS 8192
#define NCAND 256
#define DELTA 0.03f

typedef __bf16 bf16_t;
typedef bf16_t bf16x8 __attribute__((ext_vector_type(8)));
typedef float f32x4 __attribute__((ext_vector_type(4)));

__device__ __forceinline__ unsigned int sortable_key(float v) {
    unsigned int b = __float_as_uint(v);
    return (b & 0x80000000u) ? ~b : (b | 0x80000000u);
}
__device__ __forceinline__ float unkey(unsigned int key) {
    unsigned int b = (key & 0x80000000u) ? (key & 0x7FFFFFFFu) : ~key;
    return __uint_as_float(b);
}

// truncate float4 -> 4 packed bf16 (hi parts only)
__device__ __forceinline__ uint2 trunc4(float4 v) {
    unsigned int u0 = __float_as_uint(v.x), u1 = __float_as_uint(v.y);
    unsigned int u2 = __float_as_uint(v.z), u3 = __float_as_uint(v.w);
    uint2 hw;
    hw.x = (u0 >> 16) | (u1 & 0xFFFF0000u);
    hw.y = (u2 >> 16) | (u3 & 0xFFFF0000u);
    return hw;
}

// ---------------- row L2-norm ----------------
__global__ __launch_bounds__(256) void rownorm_kernel(const float* __restrict__ M,
                                                      float* __restrict__ R, int nrows) {
    int tid = threadIdx.x;
    int row = blockIdx.x * 4 + (tid >> 6);
    int lane = tid & 63;
    if (row >= nrows) return;
    const float4* p = (const float4*)(M + (size_t)row * D);
    float ss = 0.f;
#pragma unroll
    for (int i = 0; i < 4; ++i) {
        float4 v = p[lane + 64 * i];
        ss += v.x * v.x + v.y * v.y + v.z * v.z + v.w * v.w;
    }
#pragma unroll
    for (int m = 32; m >= 1; m >>= 1) ss += __shfl_xor(ss, m, 64);
    if (lane == 0) R[row] = rsqrtf(fmaxf(ss, 1e-12f));
}

// ---------------- zero packed max + candidate counters ----------------
__global__ __launch_bounds__(256) void zero_kernel(unsigned long long* __restrict__ p,
                                                   unsigned int* __restrict__ cnt, int n) {
    int i = blockIdx.x * 256 + threadIdx.x;
    if (i < n) { p[i] = 0ull; cnt[i] = 0u; }
}

// ---------------- pre-truncate X into fragment-packed bf16 hi ----------------
__global__ __launch_bounds__(256) void xsplit_kernel(const float* __restrict__ X,
                                                     ushort* __restrict__ Xhi) {
    int f = blockIdx.x * 256 + threadIdx.x;
    int row = f >> 8;
    int kq = f & 255;
    int k0 = kq * 4;
    float4 v = *((const float4*)(X + (size_t)row * D) + kq);
    uint2 hw = trunc4(v);
    int t16 = row >> 4, m = row & 15;
    int kc = k0 >> 5, kk = k0 & 31;
    int lane = m | ((kk >> 3) << 4);
    int j0 = kk & 4;
    int idx = ((t16 * 32 + kc) * 64 + lane) * 8 + j0;
    *(uint2*)(Xhi + idx) = hw;
}

// ---------------- approx sim GEMM: 1-pass bf16 hh MFMA + candidate collection ----------------
// tile 128 rows x 256 cols; A direct from pre-truncated global; B truncated in-kernel -> LDS.
// Epilogue: block row-max -> atomicMax(global running max); append cols within DELTA of it.
__global__ __launch_bounds__(256, 2) void gemm1_kernel(const ushort* __restrict__ Xhi,
                                                       const float* __restrict__ W,
                                                       const float* __restrict__ RK,
                                                       unsigned long long* __restrict__ packed,
                                                       unsigned int* __restrict__ count,
                                                       unsigned int* __restrict__ candCol) {
    __shared__ ushort Bh[2][16][64][8];
    __shared__ unsigned long long red[128][2];
    __shared__ float gthr[128];

    const int tid = threadIdx.x;
    const int l = tid & 63;
    const int wave = tid >> 6;
    const int wy = wave >> 1, wx = wave & 1;   // wave tile: 64 rows x 128 cols
    const int lin = blockIdx.x;
    const int cwTile = (lin & 7) + 8 * (lin >> 9);
    const int rowTile = (lin >> 3) & 63;
    const int rowBase = rowTile * 128;
    const int cwBase  = cwTile * 256;

    f32x4 acc[4][8];
#pragma unroll
    for (int mt = 0; mt < 4; ++mt)
#pragma unroll
        for (int nt = 0; nt < 8; ++nt) acc[mt][nt] = (f32x4)0.f;

    const float4* Wb = (const float4*)(W + (size_t)cwBase * D);

    float4 pb[8];
#pragma unroll
    for (int i = 0; i < 8; ++i) {
        int f = i * 256 + tid;
        int row = f >> 3, kq = f & 7;
        pb[i] = Wb[row * (D / 4) + kq];
    }

    const int t16base = rowTile * 8 + wy * 4;

    for (int kc = 0; kc < 32; ++kc) {
        const int b = kc & 1;
        bf16x8 ah[4];
#pragma unroll
        for (int mt = 0; mt < 4; ++mt) {
            int off = (((t16base + mt) * 32 + kc) * 64 + l) * 8;
            ah[mt] = *(const bf16x8*)(Xhi + off);
        }
#pragma unroll
        for (int i = 0; i < 8; ++i) {
            int f = i * 256 + tid;
            int row = f >> 3, kq = f & 7;
            int tile = row >> 4;
            int lf = (row & 15) | ((kq >> 1) << 4);
            int j0 = (kq & 1) * 4;
            *(uint2*)&Bh[b][tile][lf][j0] = trunc4(pb[i]);
        }
        __syncthreads();
        if (kc < 31) {
#pragma unroll
            for (int i = 0; i < 8; ++i) {
                int f = i * 256 + tid;
                int row = f >> 3, kq = f & 7;
                pb[i] = Wb[row * (D / 4) + (kc + 1) * 8 + kq];
            }
        }
#pragma unroll
        for (int nt = 0; nt < 8; ++nt) {
            bf16x8 bh = *(const bf16x8*)&Bh[b][wx * 8 + nt][l][0];
#pragma unroll
            for (int mt = 0; mt < 4; ++mt)
                acc[mt][nt] = __builtin_amdgcn_mfma_f32_16x16x32_bf16(ah[mt], bh, acc[mt][nt], 0, 0, 0);
        }
        // ping-pong: no second barrier needed (next iter's barrier fences buffer reuse)
    }

    // ---- epilogue stage 1: block-level per-row max -> global running max ----
    const int q = l >> 4, c = l & 15;
    float rk_l[8];
#pragma unroll
    for (int nt = 0; nt < 8; ++nt) rk_l[nt] = RK[cwBase + wx * 128 + nt * 16 + c];
#pragma unroll
    for (int mt = 0; mt < 4; ++mt) {
#pragma unroll
        for (int r = 0; r < 4; ++r) {
            unsigned long long pk = 0;
#pragma unroll
            for (int nt = 0; nt < 8; ++nt) {
                float v = acc[mt][nt][r] * rk_l[nt];
                int col = cwBase + wx * 128 + nt * 16 + c;
                unsigned long long p = ((unsigned long long)sortable_key(v) << 32) |
                                       (unsigned long long)(~(unsigned int)col);
                if (p > pk) pk = p;
            }
#pragma unroll
            for (int m = 1; m < 16; m <<= 1) {
                unsigned long long o = __shfl_xor(pk, m, 64);
                if (o > pk) pk = o;
            }
            if (c == 0) red[wy * 64 + mt * 16 + q * 4 + r][wx] = pk;
        }
    }
    __syncthreads();
    if (tid < 128) {
        unsigned long long a = red[tid][0], bb = red[tid][1];
        if (bb > a) a = bb;
        unsigned long long old = atomicMax(packed + (rowBase + tid), a);
        unsigned long long g = (old > a) ? old : a;
        gthr[tid] = unkey((unsigned int)(g >> 32)) - DELTA;
    }
    __syncthreads();
    // ---- epilogue stage 2: append candidates within DELTA of known running max ----
#pragma unroll
    for (int mt = 0; mt < 4; ++mt) {
#pragma unroll
        for (int r = 0; r < 4; ++r) {
            int lrow = wy * 64 + mt * 16 + q * 4 + r;
            float thr = gthr[lrow];
            int grow = rowBase + lrow;
#pragma unroll
            for (int nt = 0; nt < 8; ++nt) {
                float v = acc[mt][nt][r] * rk_l[nt];
                if (v >= thr) {
                    unsigned int slot = atomicAdd(count + grow, 1u);
                    if (slot < NCAND) {
                        int col = cwBase + wx * 128 + nt * 16 + c;
                        candCol[(size_t)grow * NCAND + slot] = (unsigned int)col;
                    }
                }
            }
        }
    }
}

// ---------------- exact fp32 rescore of candidates, final argmax ----------------
__global__ __launch_bounds__(256) void rescore_kernel(const float* __restrict__ X,
                                                      const float* __restrict__ W,
                                                      const float* __restrict__ RK,
                                                      const float* __restrict__ RQ,
                                                      const unsigned int* __restrict__ count,
                                                      const unsigned int* __restrict__ candCol,
                                                      float* __restrict__ outIdx,
                                                      float* __restrict__ outSim,
                                                      int* __restrict__ idxArr) {
    int wave = threadIdx.x >> 6, l = threadIdx.x & 63;
    int row = blockIdx.x * 4 + wave;
    unsigned int n = count[row];
    if (n > NCAND) n = NCAND;
    const float4* X4 = (const float4*)X + (size_t)row * 256;
    unsigned long long best = 0;
    for (unsigned int i = 0; i < n; ++i) {
        int col = (int)candCol[(size_t)row * NCAND + i];
        const float4* W4 = (const float4*)W + (size_t)col * 256;
        float s = 0.f;
#pragma unroll
        for (int j = 0; j < 4; ++j) {
            float4 a = X4[j * 64 + l];
            float4 b = W4[j * 64 + l];
            s += a.x * b.x + a.y * b.y + a.z * b.z + a.w * b.w;
        }
#pragma unroll
        for (int m = 32; m >= 1; m >>= 1) s += __shfl_xor(s, m, 64);
        float v = s * RK[col];
        unsigned long long pk = ((unsigned long long)sortable_key(v) << 32) |
                                (unsigned long long)(~(unsigned int)col);
        if (pk > best) best = pk;
    }
    if (l == 0) {
        int idx = (int)(~(unsigned int)(best & 0xFFFFFFFFull));
        float v = unkey((unsigned int)(best >> 32));
        outIdx[row] = (float)idx;
        outSim[row] = v * RQ[row];
        idxArr[row] = idx;
    }
}

// ---------------- per-row LN stats ----------------
__global__ __launch_bounds__(256) void ln_stats_kernel(const float* __restrict__ X,
                                                       const float* __restrict__ W,
                                                       const int* __restrict__ idxArr,
                                                       float* __restrict__ MU,
                                                       float* __restrict__ RS) {
    __shared__ float red[8];
    int row = blockIdx.x;
    int tid = threadIdx.x;
    int idx = idxArr[row];
    float4 z  = *((const float4*)(W + (size_t)idx * D) + tid);
    float4 xv = *((const float4*)(X + (size_t)row * D) + tid);
    float4 e;
    e.x = (z.x - xv.x) + xv.x;
    e.y = (z.y - xv.y) + xv.y;
    e.z = (z.z - xv.z) + xv.z;
    e.w = (z.w - xv.w) + xv.w;
    float s  = e.x + e.y + e.z + e.w;
    float s2 = e.x * e.x + e.y * e.y + e.z * e.z + e.w * e.w;
#pragma unroll
    for (int m = 32; m >= 1; m >>= 1) {
        s  += __shfl_xor(s, m, 64);
        s2 += __shfl_xor(s2, m, 64);
    }
    int wave = tid >> 6, lane = tid & 63;
    if (lane == 0) { red[wave] = s; red[4 + wave] = s2; }
    __syncthreads();
    if (tid == 0) {
        s  = red[0] + red[1] + red[2] + red[3];
        s2 = red[4] + red[5] + red[6] + red[7];
        float mean = s * (1.f / D);
        float var  = s2 * (1.f / D) - mean * mean;
        MU[row] = mean;
        RS[row] = rsqrtf(var + 1e-6f);
    }
}

// ---------------- projection GEMM: bf16 3-pass MFMA, LN fused into A staging ----------------
__global__ __launch_bounds__(256, 2) void gemm2_kernel(const float* __restrict__ X,
                                                       const float* __restrict__ W,
                                                       const int* __restrict__ idxArr,
                                                       const float* __restrict__ MU,
                                                       const float* __restrict__ RS,
                                                       const float* __restrict__ gamma,
                                                       const float* __restrict__ beta,
                                                       const float* __restrict__ B,
                                                       float* __restrict__ Out) {
    __shared__ ushort Ah[8][64][8];
    __shared__ ushort Al[8][64][8];
    __shared__ ushort Bh[8][64][8];
    __shared__ ushort Bl[8][64][8];

    const int tid = threadIdx.x;
    const int l = tid & 63;
    const int wave = tid >> 6;
    const int wy = wave >> 1, wx = wave & 1;
    const int rowBase = blockIdx.y * 128;
    const int nBase   = blockIdx.x * 128;

    f32x4 acc[4][4];
#pragma unroll
    for (int mt = 0; mt < 4; ++mt)
#pragma unroll
        for (int nt = 0; nt < 4; ++nt) acc[mt][nt] = (f32x4)0.f;

    int arow[4], aidx[4];
    float amu[4], ars[4];
#pragma unroll
    for (int i = 0; i < 4; ++i) {
        int f = i * 256 + tid;
        arow[i] = f >> 3;
        int grow = rowBase + arow[i];
        aidx[i] = idxArr[grow];
        amu[i] = MU[grow];
        ars[i] = RS[grow];
    }

    for (int kc = 0; kc < 32; ++kc) {
        __syncthreads();
#pragma unroll
        for (int i = 0; i < 4; ++i) {
            int f = i * 256 + tid;
            int row = arow[i], kq = f & 7;
            int col = kc * 32 + kq * 4;
            float4 z  = *(const float4*)(W + (size_t)aidx[i] * D + col);
            float4 xv = *(const float4*)(X + (size_t)(rowBase + row) * D + col);
            float4 g  = *(const float4*)(gamma + col);
            float4 bb = *(const float4*)(beta + col);
            float4 a;
            a.x = (((z.x - xv.x) + xv.x) - amu[i]) * ars[i] * g.x + bb.x;
            a.y = (((z.y - xv.y) + xv.y) - amu[i]) * ars[i] * g.y + bb.y;
            a.z = (((z.z - xv.z) + xv.z) - amu[i]) * ars[i] * g.z + bb.z;
            a.w = (((z.w - xv.w) + xv.w) - amu[i]) * ars[i] * g.w + bb.w;
            unsigned int u0 = __float_as_uint(a.x), u1 = __float_as_uint(a.y);
            unsigned int u2 = __float_as_uint(a.z), u3 = __float_as_uint(a.w);
            float l0 = a.x - __uint_as_float(u0 & 0xFFFF0000u);
            float l1 = a.y - __uint_as_float(u1 & 0xFFFF0000u);
            float l2 = a.z - __uint_as_float(u2 & 0xFFFF0000u);
            float l3 = a.w - __uint_as_float(u3 & 0xFFFF0000u);
            uint2 hw = {(u0 >> 16) | (u1 & 0xFFFF0000u), (u2 >> 16) | (u3 & 0xFFFF0000u)};
            uint2 lw = {(__float_as_uint(l0) >> 16) | (__float_as_uint(l1) & 0xFFFF0000u),
                        (__float_as_uint(l2) >> 16) | (__float_as_uint(l3) & 0xFFFF0000u)};
            int tile = row >> 4;
            int lf = (row & 15) | ((kq >> 1) << 4);
            int j0 = (kq & 1) * 4;
            *(uint2*)&Ah[tile][lf][j0] = hw;
            *(uint2*)&Al[tile][lf][j0] = lw;
        }
#pragma unroll
        for (int i = 0; i < 4; ++i) {
            int f = i * 256 + tid;
            int n = f & 127, dq = f >> 7;
            const float* bp = B + (size_t)(kc * 32 + dq * 4) * D + nBase + n;
            float b0 = bp[0], b1 = bp[D], b2 = bp[2 * D], b3 = bp[3 * D];
            float4 v = {b0, b1, b2, b3};
            unsigned int u0 = __float_as_uint(v.x), u1 = __float_as_uint(v.y);
            unsigned int u2 = __float_as_uint(v.z), u3 = __float_as_uint(v.w);
            float l0 = v.x - __uint_as_float(u0 & 0xFFFF0000u);
            float l1 = v.y - __uint_as_float(u1 & 0xFFFF0000u);
            float l2 = v.z - __uint_as_float(u2 & 0xFFFF0000u);
            float l3 = v.w - __uint_as_float(u3 & 0xFFFF0000u);
            uint2 hw = {(u0 >> 16) | (u1 & 0xFFFF0000u), (u2 >> 16) | (u3 & 0xFFFF0000u)};
            uint2 lw = {(__float_as_uint(l0) >> 16) | (__float_as_uint(l1) & 0xFFFF0000u),
                        (__float_as_uint(l2) >> 16) | (__float_as_uint(l3) & 0xFFFF0000u)};
            int tile = n >> 4;
            int lf = (n & 15) | ((dq >> 1) << 4);
            int j0 = (dq & 1) * 4;
            *(uint2*)&Bh[tile][lf][j0] = hw;
            *(uint2*)&Bl[tile][lf][j0] = lw;
        }
        __syncthreads();
        bf16x8 ah[4], al[4];
#pragma unroll
        for (int mt = 0; mt < 4; ++mt) {
            ah[mt] = *(const bf16x8*)&Ah[wy * 4 + mt][l][0];
            al[mt] = *(const bf16x8*)&Al[wy * 4 + mt][l][0];
        }
#pragma unroll
        for (int nt = 0; nt < 4; ++nt) {
            bf16x8 bh = *(const bf16x8*)&Bh[wx * 4 + nt][l][0];
            bf16x8 bl = *(const bf16x8*)&Bl[wx * 4 + nt][l][0];
#pragma unroll
            for (int mt = 0; mt < 4; ++mt) {
                acc[mt][nt] = __builtin_amdgcn_mfma_f32_16x16x32_bf16(ah[mt], bh, acc[mt][nt], 0, 0, 0);
                acc[mt][nt] = __builtin_amdgcn_mfma_f32_16x16x32_bf16(ah[mt], bl, acc[mt][nt], 0, 0, 0);
                acc[mt][nt] = __builtin_amdgcn_mfma_f32_16x16x32_bf16(al[mt], bh, acc[mt][nt], 0, 0, 0);
            }
        }
    }

    const int q = l >> 4, c = l & 15;
#pragma unroll
    for (int mt = 0; mt < 4; ++mt)
#pragma unroll
        for (int nt = 0; nt < 4; ++nt)
#pragma unroll
            for (int r = 0; r < 4; ++r) {
                int grow = rowBase + wy * 64 + mt * 16 + q * 4 + r;
                int gcol = nBase + wx * 64 + nt * 16 + c;
                Out[(size_t)grow * D + gcol] = acc[mt][nt][r];
            }
}

extern "C" void kernel_launch(void* const* d_in, const int* in_sizes, int n_in,
                              void* d_out, int out_size, void* d_ws, size_t ws_size,
                              hipStream_t stream) {
    const float* X     = (const float*)d_in[0];
    const float* W     = (const float*)d_in[1];
    const float* gamma = (const float*)d_in[2];
    const float* beta  = (const float*)d_in[3];
    const float* OW    = (const float*)d_in[4];

    float* out    = (float*)d_out;
    float* outIdx = out;
    float* outSim = out + NROWS;
    float* outO   = out + 2 * NROWS;

    // scratch carved from the 32 MB outO region (all consumed before gemm2 writes it):
    //   Xhi 16 MB | candCol 8 MB | count 32 KB
    ushort* Xhi = (ushort*)outO;
    unsigned int* candCol = (unsigned int*)(Xhi + (size_t)NROWS * D);
    unsigned int* count   = candCol + (size_t)NROWS * NCAND;

    // workspace — ~320 KB
    unsigned long long* packed = (unsigned long long*)d_ws;
    float* RK     = (float*)(packed + NROWS);
    float* RQ     = RK + V;
    float* MU     = RQ + NROWS;
    float* RS     = MU + NROWS;
    int*   idxArr = (int*)(RS + NROWS);

    hipLaunchKernelGGL(rownorm_kernel, dim3(V / 4), dim3(256), 0, stream, W, RK, V);
    hipLaunchKernelGGL(rownorm_kernel, dim3(NROWS / 4), dim3(256), 0, stream, X, RQ, NROWS);
    hipLaunchKernelGGL(zero_kernel, dim3(NROWS / 256), dim3(256), 0, stream, packed, count, NROWS);
    hipLaunchKernelGGL(xsplit_kernel, dim3(NROWS * (D / 4) / 256), dim3(256), 0, stream, X, Xhi);
    hipLaunchKernelGGL(gemm1_kernel, dim3((V / 256) * (NROWS / 128)), dim3(256), 0, stream,
                       Xhi, W, RK, packed, count, candCol);
    hipLaunchKernelGGL(rescore_kernel, dim3(NROWS / 4), dim3(256), 0, stream,
                       X, W, RK, RQ, count, candCol, outIdx, outSim, idxArr);
    hipLaunchKernelGGL(ln_stats_kernel, dim3(NROWS), dim3(256), 0, stream, X, W, idxArr, MU, RS);
    hipLaunchKernelGGL(gemm2_kernel, dim3(D / 128, NROWS / 128), dim3(256), 0, stream,
                       X, W, idxArr, MU, RS, gamma, beta, OW, outO);
}

// Round 7
// 723.382 us; speedup vs baseline: 1.4170x; 1.0100x over previous
//
#include <hip/hip_runtime.h>
#include <math.h>

#define D 1024
#define V 16384
#define NROWS 8192
#define NCAND 256
#define DELTA 0.03f

typedef __bf16 bf16_t;
typedef bf16_t bf16x8 __attribute__((ext_vector_type(8)));
typedef float f32x4 __attribute__((ext_vector_type(4)));

__device__ __forceinline__ unsigned int sortable_key(float v) {
    unsigned int b = __float_as_uint(v);
    return (b & 0x80000000u) ? ~b : (b | 0x80000000u);
}
__device__ __forceinline__ float unkey(unsigned int key) {
    unsigned int b = (key & 0x80000000u) ? (key & 0x7FFFFFFFu) : ~key;
    return __uint_as_float(b);
}

// truncate float4 -> 4 packed bf16 (hi parts only)
__device__ __forceinline__ uint2 trunc4(float4 v) {
    unsigned int u0 = __float_as_uint(v.x), u1 = __float_as_uint(v.y);
    unsigned int u2 = __float_as_uint(v.z), u3 = __float_as_uint(v.w);
    uint2 hw;
    hw.x = (u0 >> 16) | (u1 & 0xFFFF0000u);
    hw.y = (u2 >> 16) | (u3 & 0xFFFF0000u);
    return hw;
}

// ---------------- merged: row L2-norms of W and X + zero of packed/count ----------------
__global__ __launch_bounds__(256) void prep_kernel(const float* __restrict__ W,
                                                   const float* __restrict__ X,
                                                   float* __restrict__ RK,
                                                   float* __restrict__ RQ,
                                                   unsigned long long* __restrict__ packed,
                                                   unsigned int* __restrict__ count) {
    int tid = threadIdx.x;
    int row = blockIdx.x * 4 + (tid >> 6);
    int lane = tid & 63;
    const float* src;
    float* dst;
    int r;
    if (row < V) { src = W + (size_t)row * D; dst = RK + row; }
    else { r = row - V; src = X + (size_t)r * D; dst = RQ + r; }
    const float4* p = (const float4*)src;
    float ss = 0.f;
#pragma unroll
    for (int i = 0; i < 4; ++i) {
        float4 v = p[lane + 64 * i];
        ss += v.x * v.x + v.y * v.y + v.z * v.z + v.w * v.w;
    }
#pragma unroll
    for (int m = 32; m >= 1; m >>= 1) ss += __shfl_xor(ss, m, 64);
    if (lane == 0) {
        *dst = rsqrtf(fmaxf(ss, 1e-12f));
        if (row >= V) { packed[row - V] = 0ull; count[row - V] = 0u; }
    }
}

// ---------------- pre-truncate X into fragment-packed bf16 hi ----------------
__global__ __launch_bounds__(256) void xsplit_kernel(const float* __restrict__ X,
                                                     ushort* __restrict__ Xhi) {
    int f = blockIdx.x * 256 + threadIdx.x;
    int row = f >> 8;
    int kq = f & 255;
    int k0 = kq * 4;
    float4 v = *((const float4*)(X + (size_t)row * D) + kq);
    uint2 hw = trunc4(v);
    int t16 = row >> 4, m = row & 15;
    int kc = k0 >> 5, kk = k0 & 31;
    int lane = m | ((kk >> 3) << 4);
    int j0 = kk & 4;
    int idx = ((t16 * 32 + kc) * 64 + lane) * 8 + j0;
    *(uint2*)(Xhi + idx) = hw;
}

// ---------------- approx sim GEMM: 1-pass bf16 hh MFMA + candidate collection ----------------
// tile 128 rows x 128 cols (4 waves, 64x64 each -> acc 64 AGPR -> 3 waves/SIMD);
// A direct from pre-truncated global; B truncated in-kernel -> ping-pong LDS, 1 barrier/kc.
__global__ __launch_bounds__(256, 3) void gemm1_kernel(const ushort* __restrict__ Xhi,
                                                       const float* __restrict__ W,
                                                       const float* __restrict__ RK,
                                                       unsigned long long* __restrict__ packed,
                                                       unsigned int* __restrict__ count,
                                                       unsigned int* __restrict__ candCol) {
    __shared__ ushort Bh[2][8][64][8];
    __shared__ unsigned long long red[128][2];
    __shared__ float gthr[128];

    const int tid = threadIdx.x;
    const int l = tid & 63;
    const int wave = tid >> 6;
    const int wy = wave >> 1, wx = wave & 1;   // wave tile: 64 rows x 64 cols
    const int lin = blockIdx.x;
    const int cwTile = (lin & 7) + 8 * (lin >> 9);   // 128 col tiles, XCD-grouped
    const int rowTile = (lin >> 3) & 63;
    const int rowBase = rowTile * 128;
    const int cwBase  = cwTile * 128;

    f32x4 acc[4][4];
#pragma unroll
    for (int mt = 0; mt < 4; ++mt)
#pragma unroll
        for (int nt = 0; nt < 4; ++nt) acc[mt][nt] = (f32x4)0.f;

    const float4* Wb = (const float4*)(W + (size_t)cwBase * D);

    float4 pb[4];
#pragma unroll
    for (int i = 0; i < 4; ++i) {
        int f = i * 256 + tid;
        int row = f >> 3, kq = f & 7;
        pb[i] = Wb[row * (D / 4) + kq];
    }

    const int t16base = rowTile * 8 + wy * 4;

    for (int kc = 0; kc < 32; ++kc) {
        const int b = kc & 1;
        bf16x8 ah[4];
#pragma unroll
        for (int mt = 0; mt < 4; ++mt) {
            int off = (((t16base + mt) * 32 + kc) * 64 + l) * 8;
            ah[mt] = *(const bf16x8*)(Xhi + off);
        }
#pragma unroll
        for (int i = 0; i < 4; ++i) {
            int f = i * 256 + tid;
            int row = f >> 3, kq = f & 7;
            int tile = row >> 4;
            int lf = (row & 15) | ((kq >> 1) << 4);
            int j0 = (kq & 1) * 4;
            *(uint2*)&Bh[b][tile][lf][j0] = trunc4(pb[i]);
        }
        __syncthreads();
        if (kc < 31) {
#pragma unroll
            for (int i = 0; i < 4; ++i) {
                int f = i * 256 + tid;
                int row = f >> 3, kq = f & 7;
                pb[i] = Wb[row * (D / 4) + (kc + 1) * 8 + kq];
            }
        }
#pragma unroll
        for (int nt = 0; nt < 4; ++nt) {
            bf16x8 bh = *(const bf16x8*)&Bh[b][wx * 4 + nt][l][0];
#pragma unroll
            for (int mt = 0; mt < 4; ++mt)
                acc[mt][nt] = __builtin_amdgcn_mfma_f32_16x16x32_bf16(ah[mt], bh, acc[mt][nt], 0, 0, 0);
        }
        // ping-pong: buffer b^1 written next iter; reuse of b fenced by next barrier
    }

    // ---- epilogue stage 1: block-level per-row max -> global running max ----
    const int q = l >> 4, c = l & 15;
    float rk_l[4];
#pragma unroll
    for (int nt = 0; nt < 4; ++nt) rk_l[nt] = RK[cwBase + wx * 64 + nt * 16 + c];
#pragma unroll
    for (int mt = 0; mt < 4; ++mt) {
#pragma unroll
        for (int r = 0; r < 4; ++r) {
            unsigned long long pk = 0;
#pragma unroll
            for (int nt = 0; nt < 4; ++nt) {
                float v = acc[mt][nt][r] * rk_l[nt];
                int col = cwBase + wx * 64 + nt * 16 + c;
                unsigned long long p = ((unsigned long long)sortable_key(v) << 32) |
                                       (unsigned long long)(~(unsigned int)col);
                if (p > pk) pk = p;
            }
#pragma unroll
            for (int m = 1; m < 16; m <<= 1) {
                unsigned long long o = __shfl_xor(pk, m, 64);
                if (o > pk) pk = o;
            }
            if (c == 0) red[wy * 64 + mt * 16 + q * 4 + r][wx] = pk;
        }
    }
    __syncthreads();
    if (tid < 128) {
        unsigned long long a = red[tid][0], bb = red[tid][1];
        if (bb > a) a = bb;
        unsigned long long old = atomicMax(packed + (rowBase + tid), a);
        unsigned long long g = (old > a) ? old : a;
        gthr[tid] = unkey((unsigned int)(g >> 32)) - DELTA;
    }
    __syncthreads();
    // ---- epilogue stage 2: append candidates within DELTA of known running max ----
#pragma unroll
    for (int mt = 0; mt < 4; ++mt) {
#pragma unroll
        for (int r = 0; r < 4; ++r) {
            int lrow = wy * 64 + mt * 16 + q * 4 + r;
            float thr = gthr[lrow];
            int grow = rowBase + lrow;
#pragma unroll
            for (int nt = 0; nt < 4; ++nt) {
                float v = acc[mt][nt][r] * rk_l[nt];
                if (v >= thr) {
                    unsigned int slot = atomicAdd(count + grow, 1u);
                    if (slot < NCAND) {
                        int col = cwBase + wx * 64 + nt * 16 + c;
                        candCol[(size_t)grow * NCAND + slot] = (unsigned int)col;
                    }
                }
            }
        }
    }
}

// ---------------- exact fp32 rescore + LN stats (merged) ----------------
__global__ __launch_bounds__(256) void rescore_kernel(const float* __restrict__ X,
                                                      const float* __restrict__ W,
                                                      const float* __restrict__ RK,
                                                      const float* __restrict__ RQ,
                                                      const unsigned int* __restrict__ count,
                                                      const unsigned int* __restrict__ candCol,
                                                      float* __restrict__ outIdx,
                                                      float* __restrict__ outSim,
                                                      int* __restrict__ idxArr,
                                                      float* __restrict__ MU,
                                                      float* __restrict__ RS) {
    int wave = threadIdx.x >> 6, l = threadIdx.x & 63;
    int row = blockIdx.x * 4 + wave;
    unsigned int n = count[row];
    if (n > NCAND) n = NCAND;
    const float4* X4 = (const float4*)X + (size_t)row * 256;
    unsigned long long best = 0;
    for (unsigned int i = 0; i < n; ++i) {
        int col = (int)candCol[(size_t)row * NCAND + i];
        const float4* W4 = (const float4*)W + (size_t)col * 256;
        float s = 0.f;
#pragma unroll
        for (int j = 0; j < 4; ++j) {
            float4 a = X4[j * 64 + l];
            float4 b = W4[j * 64 + l];
            s += a.x * b.x + a.y * b.y + a.z * b.z + a.w * b.w;
        }
#pragma unroll
        for (int m = 32; m >= 1; m >>= 1) s += __shfl_xor(s, m, 64);
        float v = s * RK[col];
        unsigned long long pk = ((unsigned long long)sortable_key(v) << 32) |
                                (unsigned long long)(~(unsigned int)col);
        if (pk > best) best = pk;
    }
    // all lanes hold identical `best` (s was wave-reduced)
    int idx = (int)(~(unsigned int)(best & 0xFFFFFFFFull));
    // LN stats of e = (z - x) + x
    const float4* Z4 = (const float4*)W + (size_t)idx * 256;
    float s = 0.f, s2 = 0.f;
#pragma unroll
    for (int j = 0; j < 4; ++j) {
        float4 a = X4[j * 64 + l];
        float4 z = Z4[j * 64 + l];
        float4 e;
        e.x = (z.x - a.x) + a.x;
        e.y = (z.y - a.y) + a.y;
        e.z = (z.z - a.z) + a.z;
        e.w = (z.w - a.w) + a.w;
        s  += e.x + e.y + e.z + e.w;
        s2 += e.x * e.x + e.y * e.y + e.z * e.z + e.w * e.w;
    }
#pragma unroll
    for (int m = 32; m >= 1; m >>= 1) {
        s  += __shfl_xor(s, m, 64);
        s2 += __shfl_xor(s2, m, 64);
    }
    if (l == 0) {
        outIdx[row] = (float)idx;
        outSim[row] = unkey((unsigned int)(best >> 32)) * RQ[row];
        idxArr[row] = idx;
        float mean = s * (1.f / D);
        float var  = s2 * (1.f / D) - mean * mean;
        MU[row] = mean;
        RS[row] = rsqrtf(var + 1e-6f);
    }
}

// ---------------- projection GEMM: bf16 3-pass MFMA, LN fused into A staging ----------------
__global__ __launch_bounds__(256, 2) void gemm2_kernel(const float* __restrict__ X,
                                                       const float* __restrict__ W,
                                                       const int* __restrict__ idxArr,
                                                       const float* __restrict__ MU,
                                                       const float* __restrict__ RS,
                                                       const float* __restrict__ gamma,
                                                       const float* __restrict__ beta,
                                                       const float* __restrict__ B,
                                                       float* __restrict__ Out) {
    __shared__ ushort Ah[8][64][8];
    __shared__ ushort Al[8][64][8];
    __shared__ ushort Bh[8][64][8];
    __shared__ ushort Bl[8][64][8];

    const int tid = threadIdx.x;
    const int l = tid & 63;
    const int wave = tid >> 6;
    const int wy = wave >> 1, wx = wave & 1;
    const int rowBase = blockIdx.y * 128;
    const int nBase   = blockIdx.x * 128;

    f32x4 acc[4][4];
#pragma unroll
    for (int mt = 0; mt < 4; ++mt)
#pragma unroll
        for (int nt = 0; nt < 4; ++nt) acc[mt][nt] = (f32x4)0.f;

    int arow[4], aidx[4];
    float amu[4], ars[4];
#pragma unroll
    for (int i = 0; i < 4; ++i) {
        int f = i * 256 + tid;
        arow[i] = f >> 3;
        int grow = rowBase + arow[i];
        aidx[i] = idxArr[grow];
        amu[i] = MU[grow];
        ars[i] = RS[grow];
    }

    for (int kc = 0; kc < 32; ++kc) {
        __syncthreads();
#pragma unroll
        for (int i = 0; i < 4; ++i) {
            int f = i * 256 + tid;
            int row = arow[i], kq = f & 7;
            int col = kc * 32 + kq * 4;
            float4 z  = *(const float4*)(W + (size_t)aidx[i] * D + col);
            float4 xv = *(const float4*)(X + (size_t)(rowBase + row) * D + col);
            float4 g  = *(const float4*)(gamma + col);
            float4 bb = *(const float4*)(beta + col);
            float4 a;
            a.x = (((z.x - xv.x) + xv.x) - amu[i]) * ars[i] * g.x + bb.x;
            a.y = (((z.y - xv.y) + xv.y) - amu[i]) * ars[i] * g.y + bb.y;
            a.z = (((z.z - xv.z) + xv.z) - amu[i]) * ars[i] * g.z + bb.z;
            a.w = (((z.w - xv.w) + xv.w) - amu[i]) * ars[i] * g.w + bb.w;
            unsigned int u0 = __float_as_uint(a.x), u1 = __float_as_uint(a.y);
            unsigned int u2 = __float_as_uint(a.z), u3 = __float_as_uint(a.w);
            float l0 = a.x - __uint_as_float(u0 & 0xFFFF0000u);
            float l1 = a.y - __uint_as_float(u1 & 0xFFFF0000u);
            float l2 = a.z - __uint_as_float(u2 & 0xFFFF0000u);
            float l3 = a.w - __uint_as_float(u3 & 0xFFFF0000u);
            uint2 hw = {(u0 >> 16) | (u1 & 0xFFFF0000u), (u2 >> 16) | (u3 & 0xFFFF0000u)};
            uint2 lw = {(__float_as_uint(l0) >> 16) | (__float_as_uint(l1) & 0xFFFF0000u),
                        (__float_as_uint(l2) >> 16) | (__float_as_uint(l3) & 0xFFFF0000u)};
            int tile = row >> 4;
            int lf = (row & 15) | ((kq >> 1) << 4);
            int j0 = (kq & 1) * 4;
            *(uint2*)&Ah[tile][lf][j0] = hw;
            *(uint2*)&Al[tile][lf][j0] = lw;
        }
#pragma unroll
        for (int i = 0; i < 4; ++i) {
            int f = i * 256 + tid;
            int n = f & 127, dq = f >> 7;
            const float* bp = B + (size_t)(kc * 32 + dq * 4) * D + nBase + n;
            float b0 = bp[0], b1 = bp[D], b2 = bp[2 * D], b3 = bp[3 * D];
            float4 v = {b0, b1, b2, b3};
            unsigned int u0 = __float_as_uint(v.x), u1 = __float_as_uint(v.y);
            unsigned int u2 = __float_as_uint(v.z), u3 = __float_as_uint(v.w);
            float l0 = v.x - __uint_as_float(u0 & 0xFFFF0000u);
            float l1 = v.y - __uint_as_float(u1 & 0xFFFF0000u);
            float l2 = v.z - __uint_as_float(u2 & 0xFFFF0000u);
            float l3 = v.w - __uint_as_float(u3 & 0xFFFF0000u);
            uint2 hw = {(u0 >> 16) | (u1 & 0xFFFF0000u), (u2 >> 16) | (u3 & 0xFFFF0000u)};
            uint2 lw = {(__float_as_uint(l0) >> 16) | (__float_as_uint(l1) & 0xFFFF0000u),
                        (__float_as_uint(l2) >> 16) | (__float_as_uint(l3) & 0xFFFF0000u)};
            int tile = n >> 4;
            int lf = (n & 15) | ((dq >> 1) << 4);
            int j0 = (dq & 1) * 4;
            *(uint2*)&Bh[tile][lf][j0] = hw;
            *(uint2*)&Bl[tile][lf][j0] = lw;
        }
        __syncthreads();
        bf16x8 ah[4], al[4];
#pragma unroll
        for (int mt = 0; mt < 4; ++mt) {
            ah[mt] = *(const bf16x8*)&Ah[wy * 4 + mt][l][0];
            al[mt] = *(const bf16x8*)&Al[wy * 4 + mt][l][0];
        }
#pragma unroll
        for (int nt = 0; nt < 4; ++nt) {
            bf16x8 bh = *(const bf16x8*)&Bh[wx * 4 + nt][l][0];
            bf16x8 bl = *(const bf16x8*)&Bl[wx * 4 + nt][l][0];
#pragma unroll
            for (int mt = 0; mt < 4; ++mt) {
                acc[mt][nt] = __builtin_amdgcn_mfma_f32_16x16x32_bf16(ah[mt], bh, acc[mt][nt], 0, 0, 0);
                acc[mt][nt] = __builtin_amdgcn_mfma_f32_16x16x32_bf16(ah[mt], bl, acc[mt][nt], 0, 0, 0);
                acc[mt][nt] = __builtin_amdgcn_mfma_f32_16x16x32_bf16(al[mt], bh, acc[mt][nt], 0, 0, 0);
            }
        }
    }

    const int q = l >> 4, c = l & 15;
#pragma unroll
    for (int mt = 0; mt < 4; ++mt)
#pragma unroll
        for (int nt = 0; nt < 4; ++nt)
#pragma unroll
            for (int r = 0; r < 4; ++r) {
                int grow = rowBase + wy * 64 + mt * 16 + q * 4 + r;
                int gcol = nBase + wx * 64 + nt * 16 + c;
                Out[(size_t)grow * D + gcol] = acc[mt][nt][r];
            }
}

extern "C" void kernel_launch(void* const* d_in, const int* in_sizes, int n_in,
                              void* d_out, int out_size, void* d_ws, size_t ws_size,
                              hipStream_t stream) {
    const float* X     = (const float*)d_in[0];
    const float* W     = (const float*)d_in[1];
    const float* gamma = (const float*)d_in[2];
    const float* beta  = (const float*)d_in[3];
    const float* OW    = (const float*)d_in[4];

    float* out    = (float*)d_out;
    float* outIdx = out;
    float* outSim = out + NROWS;
    float* outO   = out + 2 * NROWS;

    // scratch carved from the 32 MB outO region (all consumed before gemm2 writes it):
    //   Xhi 16 MB | candCol 8 MB | count 32 KB
    ushort* Xhi = (ushort*)outO;
    unsigned int* candCol = (unsigned int*)(Xhi + (size_t)NROWS * D);
    unsigned int* count   = candCol + (size_t)NROWS * NCAND;

    // workspace — ~320 KB
    unsigned long long* packed = (unsigned long long*)d_ws;
    float* RK     = (float*)(packed + NROWS);
    float* RQ     = RK + V;
    float* MU     = RQ + NROWS;
    float* RS     = MU + NROWS;
    int*   idxArr = (int*)(RS + NROWS);

    hipLaunchKernelGGL(prep_kernel, dim3((V + NROWS) / 4), dim3(256), 0, stream,
                       W, X, RK, RQ, packed, count);
    hipLaunchKernelGGL(xsplit_kernel, dim3(NROWS * (D / 4) / 256), dim3(256), 0, stream, X, Xhi);
    hipLaunchKernelGGL(gemm1_kernel, dim3((V / 128) * (NROWS / 128)), dim3(256), 0, stream,
                       Xhi, W, RK, packed, count, candCol);
    hipLaunchKernelGGL(rescore_kernel, dim3(NROWS / 4), dim3(256), 0, stream,
                       X, W, RK, RQ, count, candCol, outIdx, outSim, idxArr, MU, RS);
    hipLaunchKernelGGL(gemm2_kernel, dim3(D / 128, NROWS / 128), dim3(256), 0, stream,
                       X, W, idxArr, MU, RS, gamma, beta, OW, outO);
}

// Round 8
// 654.717 us; speedup vs baseline: 1.5656x; 1.1049x over previous
//
#include <hip/hip_runtime.h>
#include <math.h>

#define D 1024
#define V 16384
#define NROWS 8192
#define NCAND 256
#define DELTA 0.03f

typedef __bf16 bf16_t;
typedef bf16_t bf16x8 __attribute__((ext_vector_type(8)));
typedef float f32x4 __attribute__((ext_vector_type(4)));

__device__ __forceinline__ unsigned int sortable_key(float v) {
    unsigned int b = __float_as_uint(v);
    return (b & 0x80000000u) ? ~b : (b | 0x80000000u);
}
__device__ __forceinline__ float unkey(unsigned int key) {
    unsigned int b = (key & 0x80000000u) ? (key & 0x7FFFFFFFu) : ~key;
    return __uint_as_float(b);
}

// truncate float4 -> 4 packed bf16 (hi parts only)
__device__ __forceinline__ uint2 trunc4(float4 v) {
    unsigned int u0 = __float_as_uint(v.x), u1 = __float_as_uint(v.y);
    unsigned int u2 = __float_as_uint(v.z), u3 = __float_as_uint(v.w);
    uint2 hw;
    hw.x = (u0 >> 16) | (u1 & 0xFFFF0000u);
    hw.y = (u2 >> 16) | (u3 & 0xFFFF0000u);
    return hw;
}
// split float4 -> bf16 hi + bf16 lo (truncation split)
__device__ __forceinline__ void split4(float4 v, uint2& hw, uint2& lw) {
    unsigned int u0 = __float_as_uint(v.x), u1 = __float_as_uint(v.y);
    unsigned int u2 = __float_as_uint(v.z), u3 = __float_as_uint(v.w);
    float l0 = v.x - __uint_as_float(u0 & 0xFFFF0000u);
    float l1 = v.y - __uint_as_float(u1 & 0xFFFF0000u);
    float l2 = v.z - __uint_as_float(u2 & 0xFFFF0000u);
    float l3 = v.w - __uint_as_float(u3 & 0xFFFF0000u);
    hw.x = (u0 >> 16) | (u1 & 0xFFFF0000u);
    hw.y = (u2 >> 16) | (u3 & 0xFFFF0000u);
    lw.x = (__float_as_uint(l0) >> 16) | (__float_as_uint(l1) & 0xFFFF0000u);
    lw.y = (__float_as_uint(l2) >> 16) | (__float_as_uint(l3) & 0xFFFF0000u);
}

// ---------------- merged: row L2-norms of W and X + zero of packed/count ----------------
__global__ __launch_bounds__(256) void prep_kernel(const float* __restrict__ W,
                                                   const float* __restrict__ X,
                                                   float* __restrict__ RK,
                                                   float* __restrict__ RQ,
                                                   unsigned long long* __restrict__ packed,
                                                   unsigned int* __restrict__ count) {
    int tid = threadIdx.x;
    int row = blockIdx.x * 4 + (tid >> 6);
    int lane = tid & 63;
    const float* src;
    float* dst;
    if (row < V) { src = W + (size_t)row * D; dst = RK + row; }
    else { src = X + (size_t)(row - V) * D; dst = RQ + (row - V); }
    const float4* p = (const float4*)src;
    float ss = 0.f;
#pragma unroll
    for (int i = 0; i < 4; ++i) {
        float4 v = p[lane + 64 * i];
        ss += v.x * v.x + v.y * v.y + v.z * v.z + v.w * v.w;
    }
#pragma unroll
    for (int m = 32; m >= 1; m >>= 1) ss += __shfl_xor(ss, m, 64);
    if (lane == 0) {
        *dst = rsqrtf(fmaxf(ss, 1e-12f));
        if (row >= V) { packed[row - V] = 0ull; count[row - V] = 0u; }
    }
}

// ---------------- pre-truncate X into fragment-packed bf16 hi ----------------
__global__ __launch_bounds__(256) void xsplit_kernel(const float* __restrict__ X,
                                                     ushort* __restrict__ Xhi) {
    int f = blockIdx.x * 256 + threadIdx.x;
    int row = f >> 8;
    int kq = f & 255;
    int k0 = kq * 4;
    float4 v = *((const float4*)(X + (size_t)row * D) + kq);
    uint2 hw = trunc4(v);
    int t16 = row >> 4, m = row & 15;
    int kc = k0 >> 5, kk = k0 & 31;
    int lane = m | ((kk >> 3) << 4);
    int j0 = kk & 4;
    int idx = ((t16 * 32 + kc) * 64 + lane) * 8 + j0;
    *(uint2*)(Xhi + idx) = hw;
}

// ---------------- approx sim GEMM: 1-pass bf16 hh MFMA + candidate collection ----------------
// 128x128 tile, 64x64/wave. ALL global loads (A-frags + W rows) prefetched one kc ahead so the
// compiler's vmcnt(0)-before-barrier drain never exposes load latency.
__global__ __launch_bounds__(256, 3) void gemm1_kernel(const ushort* __restrict__ Xhi,
                                                       const float* __restrict__ W,
                                                       const float* __restrict__ RK,
                                                       unsigned long long* __restrict__ packed,
                                                       unsigned int* __restrict__ count,
                                                       unsigned int* __restrict__ candCol) {
    __shared__ ushort Bh[2][8][64][8];
    __shared__ unsigned long long red[128][2];
    __shared__ float gthr[128];

    const int tid = threadIdx.x;
    const int l = tid & 63;
    const int wave = tid >> 6;
    const int wy = wave >> 1, wx = wave & 1;   // wave tile: 64 rows x 64 cols
    const int lin = blockIdx.x;
    const int cwTile = (lin & 7) + 8 * (lin >> 9);   // XCD-grouped col tiles
    const int rowTile = (lin >> 3) & 63;
    const int rowBase = rowTile * 128;
    const int cwBase  = cwTile * 128;

    f32x4 acc[4][4];
#pragma unroll
    for (int mt = 0; mt < 4; ++mt)
#pragma unroll
        for (int nt = 0; nt < 4; ++nt) acc[mt][nt] = (f32x4)0.f;

    const float4* Wb = (const float4*)(W + (size_t)cwBase * D);
    const int srow = tid >> 3, skq = tid & 7;   // staging row/kq for this thread (i-stride 32 rows)
    const int t16base = rowTile * 8 + wy * 4;

    // prologue: loads for kc=0
    float4 pb[4];
#pragma unroll
    for (int i = 0; i < 4; ++i) pb[i] = Wb[(srow + i * 32) * (D / 4) + skq];
    bf16x8 ah[4];
#pragma unroll
    for (int mt = 0; mt < 4; ++mt)
        ah[mt] = *(const bf16x8*)(Xhi + (((t16base + mt) * 32 + 0) * 64 + l) * 8);

    for (int kc = 0; kc < 32; ++kc) {
        const int b = kc & 1;
        // stage B from pb (current kc)
#pragma unroll
        for (int i = 0; i < 4; ++i) {
            int row = srow + i * 32;
            int tile = row >> 4;
            int lf = (row & 15) | ((skq >> 1) << 4);
            int j0 = (skq & 1) * 4;
            *(uint2*)&Bh[b][tile][lf][j0] = trunc4(pb[i]);
        }
        __syncthreads();
        // prefetch kc+1 (A-frags + W rows) — a full iteration of slack before use
        bf16x8 ahn[4];
        float4 pbn[4];
        if (kc < 31) {
#pragma unroll
            for (int mt = 0; mt < 4; ++mt)
                ahn[mt] = *(const bf16x8*)(Xhi + (((t16base + mt) * 32 + (kc + 1)) * 64 + l) * 8);
#pragma unroll
            for (int i = 0; i < 4; ++i)
                pbn[i] = Wb[(srow + i * 32) * (D / 4) + (kc + 1) * 8 + skq];
        }
#pragma unroll
        for (int nt = 0; nt < 4; ++nt) {
            bf16x8 bh = *(const bf16x8*)&Bh[b][wx * 4 + nt][l][0];
#pragma unroll
            for (int mt = 0; mt < 4; ++mt)
                acc[mt][nt] = __builtin_amdgcn_mfma_f32_16x16x32_bf16(ah[mt], bh, acc[mt][nt], 0, 0, 0);
        }
        if (kc < 31) {
#pragma unroll
            for (int mt = 0; mt < 4; ++mt) ah[mt] = ahn[mt];
#pragma unroll
            for (int i = 0; i < 4; ++i) pb[i] = pbn[i];
        }
    }

    // ---- epilogue stage 1: block-level per-row max -> global running max ----
    const int q = l >> 4, c = l & 15;
    float rk_l[4];
#pragma unroll
    for (int nt = 0; nt < 4; ++nt) rk_l[nt] = RK[cwBase + wx * 64 + nt * 16 + c];
#pragma unroll
    for (int mt = 0; mt < 4; ++mt) {
#pragma unroll
        for (int r = 0; r < 4; ++r) {
            unsigned long long pk = 0;
#pragma unroll
            for (int nt = 0; nt < 4; ++nt) {
                float v = acc[mt][nt][r] * rk_l[nt];
                int col = cwBase + wx * 64 + nt * 16 + c;
                unsigned long long p = ((unsigned long long)sortable_key(v) << 32) |
                                       (unsigned long long)(~(unsigned int)col);
                if (p > pk) pk = p;
            }
#pragma unroll
            for (int m = 1; m < 16; m <<= 1) {
                unsigned long long o = __shfl_xor(pk, m, 64);
                if (o > pk) pk = o;
            }
            if (c == 0) red[wy * 64 + mt * 16 + q * 4 + r][wx] = pk;
        }
    }
    __syncthreads();
    if (tid < 128) {
        unsigned long long a = red[tid][0], bb = red[tid][1];
        if (bb > a) a = bb;
        unsigned long long old = atomicMax(packed + (rowBase + tid), a);
        unsigned long long g = (old > a) ? old : a;
        gthr[tid] = unkey((unsigned int)(g >> 32)) - DELTA;
    }
    __syncthreads();
    // ---- epilogue stage 2: append candidates within DELTA of known running max ----
#pragma unroll
    for (int mt = 0; mt < 4; ++mt) {
#pragma unroll
        for (int r = 0; r < 4; ++r) {
            int lrow = wy * 64 + mt * 16 + q * 4 + r;
            float thr = gthr[lrow];
            int grow = rowBase + lrow;
#pragma unroll
            for (int nt = 0; nt < 4; ++nt) {
                float v = acc[mt][nt][r] * rk_l[nt];
                if (v >= thr) {
                    unsigned int slot = atomicAdd(count + grow, 1u);
                    if (slot < NCAND) {
                        int col = cwBase + wx * 64 + nt * 16 + c;
                        candCol[(size_t)grow * NCAND + slot] = (unsigned int)col;
                    }
                }
            }
        }
    }
}

// ---------------- exact fp32 rescore + LN stats (merged) ----------------
__global__ __launch_bounds__(256) void rescore_kernel(const float* __restrict__ X,
                                                      const float* __restrict__ W,
                                                      const float* __restrict__ RK,
                                                      const float* __restrict__ RQ,
                                                      const unsigned int* __restrict__ count,
                                                      const unsigned int* __restrict__ candCol,
                                                      float* __restrict__ outIdx,
                                                      float* __restrict__ outSim,
                                                      int* __restrict__ idxArr,
                                                      float* __restrict__ MU,
                                                      float* __restrict__ RS) {
    int wave = threadIdx.x >> 6, l = threadIdx.x & 63;
    int row = blockIdx.x * 4 + wave;
    unsigned int n = count[row];
    if (n > NCAND) n = NCAND;
    const float4* X4 = (const float4*)X + (size_t)row * 256;
    unsigned long long best = 0;
    for (unsigned int i = 0; i < n; ++i) {
        int col = (int)candCol[(size_t)row * NCAND + i];
        const float4* W4 = (const float4*)W + (size_t)col * 256;
        float s = 0.f;
#pragma unroll
        for (int j = 0; j < 4; ++j) {
            float4 a = X4[j * 64 + l];
            float4 b = W4[j * 64 + l];
            s += a.x * b.x + a.y * b.y + a.z * b.z + a.w * b.w;
        }
#pragma unroll
        for (int m = 32; m >= 1; m >>= 1) s += __shfl_xor(s, m, 64);
        float v = s * RK[col];
        unsigned long long pk = ((unsigned long long)sortable_key(v) << 32) |
                                (unsigned long long)(~(unsigned int)col);
        if (pk > best) best = pk;
    }
    int idx = (int)(~(unsigned int)(best & 0xFFFFFFFFull));
    const float4* Z4 = (const float4*)W + (size_t)idx * 256;
    float s = 0.f, s2 = 0.f;
#pragma unroll
    for (int j = 0; j < 4; ++j) {
        float4 a = X4[j * 64 + l];
        float4 z = Z4[j * 64 + l];
        float4 e;
        e.x = (z.x - a.x) + a.x;
        e.y = (z.y - a.y) + a.y;
        e.z = (z.z - a.z) + a.z;
        e.w = (z.w - a.w) + a.w;
        s  += e.x + e.y + e.z + e.w;
        s2 += e.x * e.x + e.y * e.y + e.z * e.z + e.w * e.w;
    }
#pragma unroll
    for (int m = 32; m >= 1; m >>= 1) {
        s  += __shfl_xor(s, m, 64);
        s2 += __shfl_xor(s2, m, 64);
    }
    if (l == 0) {
        outIdx[row] = (float)idx;
        outSim[row] = unkey((unsigned int)(best >> 32)) * RQ[row];
        idxArr[row] = idx;
        float mean = s * (1.f / D);
        float var  = s2 * (1.f / D) - mean * mean;
        MU[row] = mean;
        RS[row] = rsqrtf(var + 1e-6f);
    }
}

// ---------------- projection GEMM: bf16 3-pass MFMA, LN fused into A staging ----------------
// ping-pong LDS (1 barrier/kc); gamma/beta in LDS; z/xv/B-scalars register-prefetched 1 kc ahead.
__global__ __launch_bounds__(256, 2) void gemm2_kernel(const float* __restrict__ X,
                                                       const float* __restrict__ W,
                                                       const int* __restrict__ idxArr,
                                                       const float* __restrict__ MU,
                                                       const float* __restrict__ RS,
                                                       const float* __restrict__ gamma,
                                                       const float* __restrict__ beta,
                                                       const float* __restrict__ B,
                                                       float* __restrict__ Out) {
    __shared__ ushort Ah[2][8][64][8];
    __shared__ ushort Al[2][8][64][8];
    __shared__ ushort Bh2[2][8][64][8];
    __shared__ ushort Bl2[2][8][64][8];
    __shared__ float Gs[1024];
    __shared__ float Bt[1024];

    const int tid = threadIdx.x;
    const int l = tid & 63;
    const int wave = tid >> 6;
    const int wy = wave >> 1, wx = wave & 1;
    const int rowBase = blockIdx.y * 128;
    const int nBase   = blockIdx.x * 128;

    // gamma/beta -> LDS once
    *(float4*)&Gs[tid * 4] = *(const float4*)(gamma + tid * 4);
    *(float4*)&Bt[tid * 4] = *(const float4*)(beta + tid * 4);

    f32x4 acc[4][4];
#pragma unroll
    for (int mt = 0; mt < 4; ++mt)
#pragma unroll
        for (int nt = 0; nt < 4; ++nt) acc[mt][nt] = (f32x4)0.f;

    const int srow = tid >> 3, skq = tid & 7;   // A staging coords (i-stride 32 rows)
    const int sn = tid & 127, sdq = tid >> 7;   // B staging coords (i-stride 2 dq)
    int aidx[4];
    float amu[4], ars[4];
#pragma unroll
    for (int i = 0; i < 4; ++i) {
        int grow = rowBase + srow + i * 32;
        aidx[i] = idxArr[grow];
        amu[i] = MU[grow];
        ars[i] = RS[grow];
    }

    __syncthreads();   // Gs/Bt visible

    // prologue: loads for kc=0
    float4 pz[4], pxv[4], pbv[4];
#pragma unroll
    for (int i = 0; i < 4; ++i) {
        int col = skq * 4;
        pz[i]  = *(const float4*)(W + (size_t)aidx[i] * D + col);
        pxv[i] = *(const float4*)(X + (size_t)(rowBase + srow + i * 32) * D + col);
    }
#pragma unroll
    for (int i = 0; i < 4; ++i) {
        const float* bp = B + (size_t)((sdq + i * 2) * 4) * D + nBase + sn;
        pbv[i] = {bp[0], bp[D], bp[2 * D], bp[3 * D]};
    }

    for (int kc = 0; kc < 32; ++kc) {
        const int bsel = kc & 1;
        // stage A: STE + LN + split (inputs all in regs/LDS)
#pragma unroll
        for (int i = 0; i < 4; ++i) {
            int row = srow + i * 32;
            int col = kc * 32 + skq * 4;
            float4 z = pz[i], xv = pxv[i];
            float4 g  = *(const float4*)&Gs[col];
            float4 bb = *(const float4*)&Bt[col];
            float4 a;
            a.x = (((z.x - xv.x) + xv.x) - amu[i]) * ars[i] * g.x + bb.x;
            a.y = (((z.y - xv.y) + xv.y) - amu[i]) * ars[i] * g.y + bb.y;
            a.z = (((z.z - xv.z) + xv.z) - amu[i]) * ars[i] * g.z + bb.z;
            a.w = (((z.w - xv.w) + xv.w) - amu[i]) * ars[i] * g.w + bb.w;
            uint2 hw, lw;
            split4(a, hw, lw);
            int tile = row >> 4;
            int lf = (row & 15) | ((skq >> 1) << 4);
            int j0 = (skq & 1) * 4;
            *(uint2*)&Ah[bsel][tile][lf][j0] = hw;
            *(uint2*)&Al[bsel][tile][lf][j0] = lw;
        }
        // stage B from prefetched scalars
#pragma unroll
        for (int i = 0; i < 4; ++i) {
            int dq = sdq + i * 2;
            uint2 hw, lw;
            split4(pbv[i], hw, lw);
            int tile = sn >> 4;
            int lf = (sn & 15) | ((dq >> 1) << 4);
            int j0 = (dq & 1) * 4;
            *(uint2*)&Bh2[bsel][tile][lf][j0] = hw;
            *(uint2*)&Bl2[bsel][tile][lf][j0] = lw;
        }
        __syncthreads();
        // prefetch kc+1
        float4 pzn[4], pxvn[4], pbvn[4];
        if (kc < 31) {
#pragma unroll
            for (int i = 0; i < 4; ++i) {
                int col = (kc + 1) * 32 + skq * 4;
                pzn[i]  = *(const float4*)(W + (size_t)aidx[i] * D + col);
                pxvn[i] = *(const float4*)(X + (size_t)(rowBase + srow + i * 32) * D + col);
            }
#pragma unroll
            for (int i = 0; i < 4; ++i) {
                const float* bp = B + (size_t)((kc + 1) * 32 + (sdq + i * 2) * 4) * D + nBase + sn;
                pbvn[i] = {bp[0], bp[D], bp[2 * D], bp[3 * D]};
            }
        }
        // 3-pass MFMA from buffers [bsel]
        bf16x8 fah[4], fal[4];
#pragma unroll
        for (int mt = 0; mt < 4; ++mt) {
            fah[mt] = *(const bf16x8*)&Ah[bsel][wy * 4 + mt][l][0];
            fal[mt] = *(const bf16x8*)&Al[bsel][wy * 4 + mt][l][0];
        }
#pragma unroll
        for (int nt = 0; nt < 4; ++nt) {
            bf16x8 bh = *(const bf16x8*)&Bh2[bsel][wx * 4 + nt][l][0];
            bf16x8 bl = *(const bf16x8*)&Bl2[bsel][wx * 4 + nt][l][0];
#pragma unroll
            for (int mt = 0; mt < 4; ++mt) {
                acc[mt][nt] = __builtin_amdgcn_mfma_f32_16x16x32_bf16(fah[mt], bh, acc[mt][nt], 0, 0, 0);
                acc[mt][nt] = __builtin_amdgcn_mfma_f32_16x16x32_bf16(fah[mt], bl, acc[mt][nt], 0, 0, 0);
                acc[mt][nt] = __builtin_amdgcn_mfma_f32_16x16x32_bf16(fal[mt], bh, acc[mt][nt], 0, 0, 0);
            }
        }
        if (kc < 31) {
#pragma unroll
            for (int i = 0; i < 4; ++i) {
                pz[i] = pzn[i]; pxv[i] = pxvn[i]; pbv[i] = pbvn[i];
            }
        }
    }

    const int q = l >> 4, c = l & 15;
#pragma unroll
    for (int mt = 0; mt < 4; ++mt)
#pragma unroll
        for (int nt = 0; nt < 4; ++nt)
#pragma unroll
            for (int r = 0; r < 4; ++r) {
                int grow = rowBase + wy * 64 + mt * 16 + q * 4 + r;
                int gcol = nBase + wx * 64 + nt * 16 + c;
                Out[(size_t)grow * D + gcol] = acc[mt][nt][r];
            }
}

extern "C" void kernel_launch(void* const* d_in, const int* in_sizes, int n_in,
                              void* d_out, int out_size, void* d_ws, size_t ws_size,
                              hipStream_t stream) {
    const float* X     = (const float*)d_in[0];
    const float* W     = (const float*)d_in[1];
    const float* gamma = (const float*)d_in[2];
    const float* beta  = (const float*)d_in[3];
    const float* OW    = (const float*)d_in[4];

    float* out    = (float*)d_out;
    float* outIdx = out;
    float* outSim = out + NROWS;
    float* outO   = out + 2 * NROWS;

    // scratch carved from the 32 MB outO region (all consumed before gemm2 writes it):
    //   Xhi 16 MB | candCol 8 MB | count 32 KB
    ushort* Xhi = (ushort*)outO;
    unsigned int* candCol = (unsigned int*)(Xhi + (size_t)NROWS * D);
    unsigned int* count   = candCol + (size_t)NROWS * NCAND;

    // workspace — ~320 KB
    unsigned long long* packed = (unsigned long long*)d_ws;
    float* RK     = (float*)(packed + NROWS);
    float* RQ     = RK + V;
    float* MU     = RQ + NROWS;
    float* RS     = MU + NROWS;
    int*   idxArr = (int*)(RS + NROWS);

    hipLaunchKernelGGL(prep_kernel, dim3((V + NROWS) / 4), dim3(256), 0, stream,
                       W, X, RK, RQ, packed, count);
    hipLaunchKernelGGL(xsplit_kernel, dim3(NROWS * (D / 4) / 256), dim3(256), 0, stream, X, Xhi);
    hipLaunchKernelGGL(gemm1_kernel, dim3((V / 128) * (NROWS / 128)), dim3(256), 0, stream,
                       Xhi, W, RK, packed, count, candCol);
    hipLaunchKernelGGL(rescore_kernel, dim3(NROWS / 4), dim3(256), 0, stream,
                       X, W, RK, RQ, count, candCol, outIdx, outSim, idxArr, MU, RS);
    hipLaunchKernelGGL(gemm2_kernel, dim3(D / 128, NROWS / 128), dim3(256), 0, stream,
                       X, W, idxArr, MU, RS, gamma, beta, OW, outO);
}

// Round 9
// 642.436 us; speedup vs baseline: 1.5956x; 1.0191x over previous
//
#include <hip/hip_runtime.h>
#include <math.h>

#define D 1024
#define V 16384
#define NROWS 8192
#define NCAND 128
#define DELTA 0.03f

typedef __bf16 bf16_t;
typedef bf16_t bf16x8 __attribute__((ext_vector_type(8)));
typedef float f32x4 __attribute__((ext_vector_type(4)));

__device__ __forceinline__ unsigned int sortable_key(float v) {
    unsigned int b = __float_as_uint(v);
    return (b & 0x80000000u) ? ~b : (b | 0x80000000u);
}
__device__ __forceinline__ float unkey(unsigned int key) {
    unsigned int b = (key & 0x80000000u) ? (key & 0x7FFFFFFFu) : ~key;
    return __uint_as_float(b);
}
__device__ __forceinline__ uint2 trunc4(float4 v) {
    unsigned int u0 = __float_as_uint(v.x), u1 = __float_as_uint(v.y);
    unsigned int u2 = __float_as_uint(v.z), u3 = __float_as_uint(v.w);
    uint2 hw;
    hw.x = (u0 >> 16) | (u1 & 0xFFFF0000u);
    hw.y = (u2 >> 16) | (u3 & 0xFFFF0000u);
    return hw;
}
__device__ __forceinline__ void split4(float4 v, uint2& hw, uint2& lw) {
    unsigned int u0 = __float_as_uint(v.x), u1 = __float_as_uint(v.y);
    unsigned int u2 = __float_as_uint(v.z), u3 = __float_as_uint(v.w);
    float l0 = v.x - __uint_as_float(u0 & 0xFFFF0000u);
    float l1 = v.y - __uint_as_float(u1 & 0xFFFF0000u);
    float l2 = v.z - __uint_as_float(u2 & 0xFFFF0000u);
    float l3 = v.w - __uint_as_float(u3 & 0xFFFF0000u);
    hw.x = (u0 >> 16) | (u1 & 0xFFFF0000u);
    hw.y = (u2 >> 16) | (u3 & 0xFFFF0000u);
    lw.x = (__float_as_uint(l0) >> 16) | (__float_as_uint(l1) & 0xFFFF0000u);
    lw.y = (__float_as_uint(l2) >> 16) | (__float_as_uint(l3) & 0xFFFF0000u);
}

// ---------------- merged: row L2-norms of W and X + zero of packed/count ----------------
__global__ __launch_bounds__(256) void prep_kernel(const float* __restrict__ W,
                                                   const float* __restrict__ X,
                                                   float* __restrict__ RK,
                                                   float* __restrict__ RQ,
                                                   unsigned long long* __restrict__ packed,
                                                   unsigned int* __restrict__ count) {
    int tid = threadIdx.x;
    int row = blockIdx.x * 4 + (tid >> 6);
    int lane = tid & 63;
    const float* src;
    float* dst;
    if (row < V) { src = W + (size_t)row * D; dst = RK + row; }
    else { src = X + (size_t)(row - V) * D; dst = RQ + (row - V); }
    const float4* p = (const float4*)src;
    float ss = 0.f;
#pragma unroll
    for (int i = 0; i < 4; ++i) {
        float4 v = p[lane + 64 * i];
        ss += v.x * v.x + v.y * v.y + v.z * v.z + v.w * v.w;
    }
#pragma unroll
    for (int m = 32; m >= 1; m >>= 1) ss += __shfl_xor(ss, m, 64);
    if (lane == 0) {
        *dst = rsqrtf(fmaxf(ss, 1e-12f));
        if (row >= V) { packed[row - V] = 0ull; count[row - V] = 0u; }
    }
}

// ---------------- truncate rows of src into MFMA-fragment-packed bf16 ----------------
// dst[((t16*32 + kc)*64 + lane)*8 + j]: t16=row>>4, lane=(row&15)|((kk>>3)<<4), j=kk&7 (kk=k&31)
// generic over row base: used for X (8192 rows) and W chunks.
__global__ __launch_bounds__(256) void pack_kernel(const float* __restrict__ src,
                                                   ushort* __restrict__ dst) {
    int f = blockIdx.x * 256 + threadIdx.x;
    int row = f >> 8;
    int kq = f & 255;
    int k0 = kq * 4;
    float4 v = *((const float4*)(src + (size_t)row * D) + kq);
    uint2 hw = trunc4(v);
    int t16 = row >> 4, m = row & 15;
    int kc = k0 >> 5, kk = k0 & 31;
    int lane = m | ((kk >> 3) << 4);
    int j0 = kk & 4;
    int idx = ((t16 * 32 + kc) * 64 + lane) * 8 + j0;
    *(uint2*)(dst + idx) = hw;
}

// ---------------- approx sim GEMM: barrier-free K-loop, frags direct from global ----------------
// 128x128 block tile, 64x64/wave. No LDS staging, no __syncthreads in K-loop, no split VALU.
// Swizzle: xcd = lin&7 serves cols [colBase + xcd*perX*128, +perX*128) -> B slice L2-resident.
__global__ __launch_bounds__(256, 3) void gemm1_kernel(const ushort* __restrict__ Xhi,
                                                       const ushort* __restrict__ Wfrag,
                                                       const float* __restrict__ RK,
                                                       unsigned long long* __restrict__ packed,
                                                       unsigned int* __restrict__ count,
                                                       ushort* __restrict__ candCol,
                                                       int colBase, int perX) {
    __shared__ unsigned long long red[128][2];
    __shared__ float gthr[128];

    const int tid = threadIdx.x;
    const int l = tid & 63;
    const int wave = tid >> 6;
    const int wy = wave >> 1, wx = wave & 1;   // wave tile: 64 rows x 64 cols
    const int lin = blockIdx.x;
    const int x = lin & 7;
    const int j = lin >> 3;
    const int rt = j / perX;
    const int ctl = x * perX + (j - rt * perX);
    const int rowBase = rt * 128;
    const int cwLocal = ctl * 128;

    f32x4 acc[4][4];
#pragma unroll
    for (int mt = 0; mt < 4; ++mt)
#pragma unroll
        for (int nt = 0; nt < 4; ++nt) acc[mt][nt] = (f32x4)0.f;

    // element-offset bases; frag(mt/nt, kc) = base + t*16384 + kc*512
    const ushort* Ab = Xhi + ((size_t)(rt * 8 + wy * 4) * 16384) + l * 8;
    const ushort* Bb = Wfrag + ((size_t)(ctl * 8 + wx * 4) * 16384) + l * 8;

    bf16x8 a0[4], b0[4], a1[4], b1[4];
#pragma unroll
    for (int t = 0; t < 4; ++t) {
        a0[t] = *(const bf16x8*)(Ab + t * 16384);
        b0[t] = *(const bf16x8*)(Bb + t * 16384);
    }

    for (int kc = 0; kc < 32; kc += 2) {
        if (kc + 1 < 32) {
#pragma unroll
            for (int t = 0; t < 4; ++t) {
                a1[t] = *(const bf16x8*)(Ab + t * 16384 + (kc + 1) * 512);
                b1[t] = *(const bf16x8*)(Bb + t * 16384 + (kc + 1) * 512);
            }
        }
#pragma unroll
        for (int nt = 0; nt < 4; ++nt)
#pragma unroll
            for (int mt = 0; mt < 4; ++mt)
                acc[mt][nt] = __builtin_amdgcn_mfma_f32_16x16x32_bf16(a0[mt], b0[nt], acc[mt][nt], 0, 0, 0);
        if (kc + 2 < 32) {
#pragma unroll
            for (int t = 0; t < 4; ++t) {
                a0[t] = *(const bf16x8*)(Ab + t * 16384 + (kc + 2) * 512);
                b0[t] = *(const bf16x8*)(Bb + t * 16384 + (kc + 2) * 512);
            }
        }
#pragma unroll
        for (int nt = 0; nt < 4; ++nt)
#pragma unroll
            for (int mt = 0; mt < 4; ++mt)
                acc[mt][nt] = __builtin_amdgcn_mfma_f32_16x16x32_bf16(a1[mt], b1[nt], acc[mt][nt], 0, 0, 0);
    }

    // ---- epilogue stage 1: block-level per-row max -> global running max ----
    const int q = l >> 4, c = l & 15;
    float rk_l[4];
#pragma unroll
    for (int nt = 0; nt < 4; ++nt) rk_l[nt] = RK[colBase + cwLocal + wx * 64 + nt * 16 + c];
#pragma unroll
    for (int mt = 0; mt < 4; ++mt) {
#pragma unroll
        for (int r = 0; r < 4; ++r) {
            unsigned long long pk = 0;
#pragma unroll
            for (int nt = 0; nt < 4; ++nt) {
                float v = acc[mt][nt][r] * rk_l[nt];
                int col = colBase + cwLocal + wx * 64 + nt * 16 + c;
                unsigned long long p = ((unsigned long long)sortable_key(v) << 32) |
                                       (unsigned long long)(~(unsigned int)col);
                if (p > pk) pk = p;
            }
#pragma unroll
            for (int m = 1; m < 16; m <<= 1) {
                unsigned long long o = __shfl_xor(pk, m, 64);
                if (o > pk) pk = o;
            }
            if (c == 0) red[wy * 64 + mt * 16 + q * 4 + r][wx] = pk;
        }
    }
    __syncthreads();
    if (tid < 128) {
        unsigned long long a = red[tid][0], bb = red[tid][1];
        if (bb > a) a = bb;
        unsigned long long old = atomicMax(packed + (rowBase + tid), a);
        unsigned long long g = (old > a) ? old : a;
        gthr[tid] = unkey((unsigned int)(g >> 32)) - DELTA;
    }
    __syncthreads();
    // ---- epilogue stage 2: append candidates within DELTA of known running max ----
#pragma unroll
    for (int mt = 0; mt < 4; ++mt) {
#pragma unroll
        for (int r = 0; r < 4; ++r) {
            int lrow = wy * 64 + mt * 16 + q * 4 + r;
            float thr = gthr[lrow];
            int grow = rowBase + lrow;
#pragma unroll
            for (int nt = 0; nt < 4; ++nt) {
                float v = acc[mt][nt][r] * rk_l[nt];
                if (v >= thr) {
                    unsigned int slot = atomicAdd(count + grow, 1u);
                    if (slot < NCAND) {
                        int col = colBase + cwLocal + wx * 64 + nt * 16 + c;
                        candCol[(size_t)grow * NCAND + slot] = (ushort)col;
                    }
                }
            }
        }
    }
}

// ---------------- exact fp32 rescore + LN stats (merged) ----------------
__global__ __launch_bounds__(256) void rescore_kernel(const float* __restrict__ X,
                                                      const float* __restrict__ W,
                                                      const float* __restrict__ RK,
                                                      const float* __restrict__ RQ,
                                                      const unsigned int* __restrict__ count,
                                                      const ushort* __restrict__ candCol,
                                                      float* __restrict__ outIdx,
                                                      float* __restrict__ outSim,
                                                      int* __restrict__ idxArr,
                                                      float* __restrict__ MU,
                                                      float* __restrict__ RS) {
    int wave = threadIdx.x >> 6, l = threadIdx.x & 63;
    int row = blockIdx.x * 4 + wave;
    unsigned int n = count[row];
    if (n > NCAND) n = NCAND;
    const float4* X4 = (const float4*)X + (size_t)row * 256;
    unsigned long long best = 0;
    for (unsigned int i = 0; i < n; ++i) {
        int col = (int)candCol[(size_t)row * NCAND + i];
        const float4* W4 = (const float4*)W + (size_t)col * 256;
        float s = 0.f;
#pragma unroll
        for (int jj = 0; jj < 4; ++jj) {
            float4 a = X4[jj * 64 + l];
            float4 b = W4[jj * 64 + l];
            s += a.x * b.x + a.y * b.y + a.z * b.z + a.w * b.w;
        }
#pragma unroll
        for (int m = 32; m >= 1; m >>= 1) s += __shfl_xor(s, m, 64);
        float v = s * RK[col];
        unsigned long long pk = ((unsigned long long)sortable_key(v) << 32) |
                                (unsigned long long)(~(unsigned int)col);
        if (pk > best) best = pk;
    }
    int idx = (int)(~(unsigned int)(best & 0xFFFFFFFFull)) & 0xFFFF;
    const float4* Z4 = (const float4*)W + (size_t)idx * 256;
    float s = 0.f, s2 = 0.f;
#pragma unroll
    for (int jj = 0; jj < 4; ++jj) {
        float4 a = X4[jj * 64 + l];
        float4 z = Z4[jj * 64 + l];
        float4 e;
        e.x = (z.x - a.x) + a.x;
        e.y = (z.y - a.y) + a.y;
        e.z = (z.z - a.z) + a.z;
        e.w = (z.w - a.w) + a.w;
        s  += e.x + e.y + e.z + e.w;
        s2 += e.x * e.x + e.y * e.y + e.z * e.z + e.w * e.w;
    }
#pragma unroll
    for (int m = 32; m >= 1; m >>= 1) {
        s  += __shfl_xor(s, m, 64);
        s2 += __shfl_xor(s2, m, 64);
    }
    if (l == 0) {
        outIdx[row] = (float)idx;
        outSim[row] = unkey((unsigned int)(best >> 32)) * RQ[row];
        idxArr[row] = idx;
        float mean = s * (1.f / D);
        float var  = s2 * (1.f / D) - mean * mean;
        MU[row] = mean;
        RS[row] = rsqrtf(var + 1e-6f);
    }
}

// ---------------- projection GEMM: bf16 3-pass MFMA, LN fused into A staging ----------------
__global__ __launch_bounds__(256, 2) void gemm2_kernel(const float* __restrict__ X,
                                                       const float* __restrict__ W,
                                                       const int* __restrict__ idxArr,
                                                       const float* __restrict__ MU,
                                                       const float* __restrict__ RS,
                                                       const float* __restrict__ gamma,
                                                       const float* __restrict__ beta,
                                                       const float* __restrict__ B,
                                                       float* __restrict__ Out) {
    __shared__ ushort Ah[2][8][64][8];
    __shared__ ushort Al[2][8][64][8];
    __shared__ ushort Bh2[2][8][64][8];
    __shared__ ushort Bl2[2][8][64][8];
    __shared__ float Gs[1024];
    __shared__ float Bt[1024];

    const int tid = threadIdx.x;
    const int l = tid & 63;
    const int wave = tid >> 6;
    const int wy = wave >> 1, wx = wave & 1;
    const int rowBase = blockIdx.y * 128;
    const int nBase   = blockIdx.x * 128;

    *(float4*)&Gs[tid * 4] = *(const float4*)(gamma + tid * 4);
    *(float4*)&Bt[tid * 4] = *(const float4*)(beta + tid * 4);

    f32x4 acc[4][4];
#pragma unroll
    for (int mt = 0; mt < 4; ++mt)
#pragma unroll
        for (int nt = 0; nt < 4; ++nt) acc[mt][nt] = (f32x4)0.f;

    const int srow = tid >> 3, skq = tid & 7;
    const int sn = tid & 127, sdq = tid >> 7;
    int aidx[4];
    float amu[4], ars[4];
#pragma unroll
    for (int i = 0; i < 4; ++i) {
        int grow = rowBase + srow + i * 32;
        aidx[i] = idxArr[grow];
        amu[i] = MU[grow];
        ars[i] = RS[grow];
    }

    __syncthreads();

    float4 pz[4], pxv[4], pbv[4];
#pragma unroll
    for (int i = 0; i < 4; ++i) {
        int col = skq * 4;
        pz[i]  = *(const float4*)(W + (size_t)aidx[i] * D + col);
        pxv[i] = *(const float4*)(X + (size_t)(rowBase + srow + i * 32) * D + col);
    }
#pragma unroll
    for (int i = 0; i < 4; ++i) {
        const float* bp = B + (size_t)((sdq + i * 2) * 4) * D + nBase + sn;
        pbv[i] = {bp[0], bp[D], bp[2 * D], bp[3 * D]};
    }

    for (int kc = 0; kc < 32; ++kc) {
        const int bsel = kc & 1;
#pragma unroll
        for (int i = 0; i < 4; ++i) {
            int row = srow + i * 32;
            int col = kc * 32 + skq * 4;
            float4 z = pz[i], xv = pxv[i];
            float4 g  = *(const float4*)&Gs[col];
            float4 bb = *(const float4*)&Bt[col];
            float4 a;
            a.x = (((z.x - xv.x) + xv.x) - amu[i]) * ars[i] * g.x + bb.x;
            a.y = (((z.y - xv.y) + xv.y) - amu[i]) * ars[i] * g.y + bb.y;
            a.z = (((z.z - xv.z) + xv.z) - amu[i]) * ars[i] * g.z + bb.z;
            a.w = (((z.w - xv.w) + xv.w) - amu[i]) * ars[i] * g.w + bb.w;
            uint2 hw, lw;
            split4(a, hw, lw);
            int tile = row >> 4;
            int lf = (row & 15) | ((skq >> 1) << 4);
            int j0 = (skq & 1) * 4;
            *(uint2*)&Ah[bsel][tile][lf][j0] = hw;
            *(uint2*)&Al[bsel][tile][lf][j0] = lw;
        }
#pragma unroll
        for (int i = 0; i < 4; ++i) {
            int dq = sdq + i * 2;
            uint2 hw, lw;
            split4(pbv[i], hw, lw);
            int tile = sn >> 4;
            int lf = (sn & 15) | ((dq >> 1) << 4);
            int j0 = (dq & 1) * 4;
            *(uint2*)&Bh2[bsel][tile][lf][j0] = hw;
            *(uint2*)&Bl2[bsel][tile][lf][j0] = lw;
        }
        __syncthreads();
        float4 pzn[4], pxvn[4], pbvn[4];
        if (kc < 31) {
#pragma unroll
            for (int i = 0; i < 4; ++i) {
                int col = (kc + 1) * 32 + skq * 4;
                pzn[i]  = *(const float4*)(W + (size_t)aidx[i] * D + col);
                pxvn[i] = *(const float4*)(X + (size_t)(rowBase + srow + i * 32) * D + col);
            }
#pragma unroll
            for (int i = 0; i < 4; ++i) {
                const float* bp = B + (size_t)((kc + 1) * 32 + (sdq + i * 2) * 4) * D + nBase + sn;
                pbvn[i] = {bp[0], bp[D], bp[2 * D], bp[3 * D]};
            }
        }
        bf16x8 fah[4], fal[4];
#pragma unroll
        for (int mt = 0; mt < 4; ++mt) {
            fah[mt] = *(const bf16x8*)&Ah[bsel][wy * 4 + mt][l][0];
            fal[mt] = *(const bf16x8*)&Al[bsel][wy * 4 + mt][l][0];
        }
#pragma unroll
        for (int nt = 0; nt < 4; ++nt) {
            bf16x8 bh = *(const bf16x8*)&Bh2[bsel][wx * 4 + nt][l][0];
            bf16x8 bl = *(const bf16x8*)&Bl2[bsel][wx * 4 + nt][l][0];
#pragma unroll
            for (int mt = 0; mt < 4; ++mt) {
                acc[mt][nt] = __builtin_amdgcn_mfma_f32_16x16x32_bf16(fah[mt], bh, acc[mt][nt], 0, 0, 0);
                acc[mt][nt] = __builtin_amdgcn_mfma_f32_16x16x32_bf16(fah[mt], bl, acc[mt][nt], 0, 0, 0);
                acc[mt][nt] = __builtin_amdgcn_mfma_f32_16x16x32_bf16(fal[mt], bh, acc[mt][nt], 0, 0, 0);
            }
        }
        if (kc < 31) {
#pragma unroll
            for (int i = 0; i < 4; ++i) {
                pz[i] = pzn[i]; pxv[i] = pxvn[i]; pbv[i] = pbvn[i];
            }
        }
    }

    const int q = l >> 4, c = l & 15;
#pragma unroll
    for (int mt = 0; mt < 4; ++mt)
#pragma unroll
        for (int nt = 0; nt < 4; ++nt)
#pragma unroll
            for (int r = 0; r < 4; ++r) {
                int grow = rowBase + wy * 64 + mt * 16 + q * 4 + r;
                int gcol = nBase + wx * 64 + nt * 16 + c;
                Out[(size_t)grow * D + gcol] = acc[mt][nt][r];
            }
}

extern "C" void kernel_launch(void* const* d_in, const int* in_sizes, int n_in,
                              void* d_out, int out_size, void* d_ws, size_t ws_size,
                              hipStream_t stream) {
    const float* X     = (const float*)d_in[0];
    const float* W     = (const float*)d_in[1];
    const float* gamma = (const float*)d_in[2];
    const float* beta  = (const float*)d_in[3];
    const float* OW    = (const float*)d_in[4];

    float* out    = (float*)d_out;
    float* outIdx = out;
    float* outSim = out + NROWS;
    float* outO   = out + 2 * NROWS;

    // scratch carved from the 32 MB outO region (all consumed before gemm2 writes it):
    //   Xhi 16 MB | Wfrag 12 MB (per-chunk, reused) | candCol u16 2 MB | count 32 KB
    ushort* Xhi   = (ushort*)outO;
    ushort* Wfrag = Xhi + (size_t)NROWS * D;                    // 12 MB = 6144 rows max
    ushort* candCol = Wfrag + (size_t)6144 * D;
    unsigned int* count = (unsigned int*)(candCol + (size_t)NROWS * NCAND);

    // workspace — ~320 KB
    unsigned long long* packed = (unsigned long long*)d_ws;
    float* RK     = (float*)(packed + NROWS);
    float* RQ     = RK + V;
    float* MU     = RQ + NROWS;
    float* RS     = MU + NROWS;
    int*   idxArr = (int*)(RS + NROWS);

    hipLaunchKernelGGL(prep_kernel, dim3((V + NROWS) / 4), dim3(256), 0, stream,
                       W, X, RK, RQ, packed, count);
    hipLaunchKernelGGL(pack_kernel, dim3(NROWS), dim3(256), 0, stream, X, Xhi);

    // W chunks: 6144, 6144, 4096 codebook rows
    const int chunkRows[3] = {6144, 6144, 4096};
    int colBase = 0;
    for (int ch = 0; ch < 3; ++ch) {
        int rows = chunkRows[ch];
        int perX = (rows / 128) / 8;   // col-tiles per XCD: 6, 6, 4
        hipLaunchKernelGGL(pack_kernel, dim3(rows), dim3(256), 0, stream,
                           W + (size_t)colBase * D, Wfrag);
        hipLaunchKernelGGL(gemm1_kernel, dim3((NROWS / 128) * (rows / 128)), dim3(256), 0, stream,
                           Xhi, Wfrag, RK, packed, count, candCol, colBase, perX);
        colBase += rows;
    }

    hipLaunchKernelGGL(rescore_kernel, dim3(NROWS / 4), dim3(256), 0, stream,
                       X, W, RK, RQ, count, candCol, outIdx, outSim, idxArr, MU, RS);
    hipLaunchKernelGGL(gemm2_kernel, dim3(D / 128, NROWS / 128), dim3(256), 0, stream,
                       X, W, idxArr, MU, RS, gamma, beta, OW, outO);
}